// Round 1
// baseline (1272.271 us; speedup 1.0000x reference)
//
#include <hip/hip_runtime.h>

#define NKEYS  100000
#define BQ     1024
#define EPS_F  1e-6f
#define NCHUNK 32
#define CHUNKK 3136   // 49 * 64; 32 chunks cover 100352 >= 100000
#define BIGF   1e30f

// Insert (nd, ni) into ascending sorted 5-list. Fully unrolled -> stays in VGPRs.
__device__ __forceinline__ void ins5(float (&d)[5], int (&ix)[5], float nd, int ni) {
    if (nd < d[4]) {
        d[4] = nd; ix[4] = ni;
#pragma unroll
        for (int p = 4; p > 0; --p) {
            if (d[p] < d[p - 1]) {
                float td = d[p]; d[p] = d[p - 1]; d[p - 1] = td;
                int   ti = ix[p]; ix[p] = ix[p - 1]; ix[p - 1] = ti;
            }
        }
    }
}

// C[M,N] = act(A[M,K] @ W[K,N] + bias). 64x64 tile, 256 threads, 4x4/thread.
// Requires M,N multiples of 64; K multiple of 16 (true for all 6 layers here).
template <int RELU>
__global__ __launch_bounds__(256)
void sgemm_bias(const float* __restrict__ A, const float* __restrict__ W,
                const float* __restrict__ bias, float* __restrict__ C,
                int M, int N, int K) {
    __shared__ float As[16][68];   // transposed A tile: As[k][m], pad 68 keeps stores ~conflict-free + 16B-aligned reads
    __shared__ float Bs[16][64];   // Bs[k][n]
    const int tid = threadIdx.x;
    const int tx = tid & 15, ty = tid >> 4;
    const int m0 = blockIdx.y * 64, n0 = blockIdx.x * 64;
    float acc[4][4] = {};
    for (int k0 = 0; k0 < K; k0 += 16) {
        {   // A tile 64x16 -> transposed store
            int m  = tid >> 2;
            int k4 = (tid & 3) * 4;
            float4 a = *(const float4*)&A[(size_t)(m0 + m) * K + k0 + k4];
            As[k4 + 0][m] = a.x; As[k4 + 1][m] = a.y;
            As[k4 + 2][m] = a.z; As[k4 + 3][m] = a.w;
        }
        {   // B tile 16x64 -> direct store
            int k  = tid >> 4;
            int n4 = (tid & 15) * 4;
            *(float4*)&Bs[k][n4] = *(const float4*)&W[(size_t)(k0 + k) * N + n0 + n4];
        }
        __syncthreads();
#pragma unroll
        for (int kk = 0; kk < 16; ++kk) {
            float4 a4 = *(const float4*)&As[kk][ty * 4];
            float4 b4 = *(const float4*)&Bs[kk][tx * 4];
            float av[4] = {a4.x, a4.y, a4.z, a4.w};
            float bv[4] = {b4.x, b4.y, b4.z, b4.w};
#pragma unroll
            for (int i = 0; i < 4; ++i)
#pragma unroll
                for (int j = 0; j < 4; ++j)
                    acc[i][j] = fmaf(av[i], bv[j], acc[i][j]);
        }
        __syncthreads();
    }
    float4 b4 = *(const float4*)&bias[n0 + tx * 4];
    float bb[4] = {b4.x, b4.y, b4.z, b4.w};
#pragma unroll
    for (int i = 0; i < 4; ++i) {
        float ov[4];
#pragma unroll
        for (int j = 0; j < 4; ++j) {
            float v = acc[i][j] + bb[j];
            if (RELU) v = fmaxf(v, 0.0f);
            ov[j] = v;
        }
        *(float4*)&C[(size_t)(m0 + ty * 4 + i) * N + n0 + tx * 4] =
            make_float4(ov[0], ov[1], ov[2], ov[3]);
    }
}

// out[row] = sum_c X[row][c]^2, D=128 fixed. One wave per row, 4 rows/block.
__global__ __launch_bounds__(256)
void rowsq128(const float* __restrict__ X, float* __restrict__ out, int nrows) {
    int lane = threadIdx.x & 63;
    int row  = blockIdx.x * 4 + (threadIdx.x >> 6);
    if (row >= nrows) return;
    const float* x = X + (size_t)row * 128;
    float a = x[lane], b = x[lane + 64];
    float v = a * a + b * b;
#pragma unroll
    for (int off = 32; off > 0; off >>= 1) v += __shfl_down(v, off, 64);
    if (lane == 0) out[row] = v;
}

// Fused distance + per-chunk top-5. grid = (NCHUNK, BQ/64), block 256.
// Per block: 64 query rows x one key chunk. Q tile resident in LDS; 64-key
// tiles streamed. d2 = qq + kk - 2*S. Per-thread sorted top-5 per row,
// block-merged at the end -> 5 candidates per (row, chunk) to workspace.
__global__ __launch_bounds__(256)
void dist_topk(const float* __restrict__ cq, const float* __restrict__ keys,
               const float* __restrict__ kk, const float* __restrict__ qq,
               float* __restrict__ cand_d, int* __restrict__ cand_i) {
    __shared__ union SU {
        struct { float Qs[128][64]; float Ks[128][64]; } t;  // 64 KiB, inner reads conflict-free
        struct { float d[64][80]; int i[64][80]; } m;        // 40 KiB merge scratch (reuses tiles)
    } S;
    const int tid = threadIdx.x;
    const int tx = tid & 15, ty = tid >> 4;
    const int m0   = blockIdx.y * 64;
    const int c0   = blockIdx.x * CHUNKK;
    const int cEnd = min(c0 + CHUNKK, NKEYS);

    {   // Q tile [64 rows][128 dims] -> transposed Qs[k][r]
        int lr = tid >> 5;          // 0..7
        int c4 = (tid & 31) * 4;    // 0..124
#pragma unroll
        for (int s = 0; s < 8; ++s) {
            int r = s * 8 + lr;
            float4 q = *(const float4*)&cq[(size_t)(m0 + r) * 128 + c4];
            S.t.Qs[c4 + 0][r] = q.x; S.t.Qs[c4 + 1][r] = q.y;
            S.t.Qs[c4 + 2][r] = q.z; S.t.Qs[c4 + 3][r] = q.w;
        }
    }
    float qq_r[4];
#pragma unroll
    for (int i = 0; i < 4; ++i) qq_r[i] = qq[m0 + ty * 4 + i];

    float t5d[4][5]; int t5i[4][5];
#pragma unroll
    for (int i = 0; i < 4; ++i)
#pragma unroll
        for (int p = 0; p < 5; ++p) { t5d[i][p] = BIGF; t5i[i][p] = 0; }

    for (int n0 = c0; n0 < cEnd; n0 += 64) {
        __syncthreads();   // previous iter's Ks reads done
        {
            int lr = tid >> 5;
            int c4 = (tid & 31) * 4;
#pragma unroll
            for (int s = 0; s < 8; ++s) {
                int r = s * 8 + lr;
                int n = n0 + r;
                float4 kv = make_float4(0.f, 0.f, 0.f, 0.f);
                if (n < NKEYS) kv = *(const float4*)&keys[(size_t)n * 128 + c4];
                S.t.Ks[c4 + 0][r] = kv.x; S.t.Ks[c4 + 1][r] = kv.y;
                S.t.Ks[c4 + 2][r] = kv.z; S.t.Ks[c4 + 3][r] = kv.w;
            }
        }
        __syncthreads();
        float acc[4][4] = {};
#pragma unroll 8
        for (int k = 0; k < 128; ++k) {
            float4 a4 = *(const float4*)&S.t.Qs[k][ty * 4];
            float4 b4 = *(const float4*)&S.t.Ks[k][tx * 4];
            float av[4] = {a4.x, a4.y, a4.z, a4.w};
            float bv[4] = {b4.x, b4.y, b4.z, b4.w};
#pragma unroll
            for (int i = 0; i < 4; ++i)
#pragma unroll
                for (int j = 0; j < 4; ++j)
                    acc[i][j] = fmaf(av[i], bv[j], acc[i][j]);
        }
        float kk_r[4];
#pragma unroll
        for (int j = 0; j < 4; ++j) {
            int n = n0 + tx * 4 + j;
            kk_r[j] = (n < cEnd) ? kk[n] : BIGF;  // exclude out-of-chunk / padded keys
        }
#pragma unroll
        for (int i = 0; i < 4; ++i)
#pragma unroll
            for (int j = 0; j < 4; ++j) {
                float d = qq_r[i] + kk_r[j] - 2.0f * acc[i][j];
                ins5(t5d[i], t5i[i], d, n0 + tx * 4 + j);
            }
    }

    __syncthreads();   // all compute done before union repurpose
#pragma unroll
    for (int i = 0; i < 4; ++i)
#pragma unroll
        for (int p = 0; p < 5; ++p) {
            S.m.d[ty * 4 + i][tx * 5 + p] = t5d[i][p];
            S.m.i[ty * 4 + i][tx * 5 + p] = t5i[i][p];
        }
    __syncthreads();
    if (tid < 64) {
        float bd[5]; int bi[5];
#pragma unroll
        for (int p = 0; p < 5; ++p) { bd[p] = BIGF; bi[p] = 0; }
        for (int c = 0; c < 80; ++c) ins5(bd, bi, S.m.d[tid][c], S.m.i[tid][c]);
        int gr = m0 + tid;
#pragma unroll
        for (int p = 0; p < 5; ++p) {
            cand_d[((size_t)gr * NCHUNK + blockIdx.x) * 5 + p] = bd[p];
            cand_i[((size_t)gr * NCHUNK + blockIdx.x) * 5 + p] = bi[p];
        }
    }
}

// Per row: merge 160 candidates -> top-5, softmax-of-inverse-distance weights,
// gather values rows, write weighted [row][128] and confidence.
__global__ __launch_bounds__(192)
void merge_gather(const float* __restrict__ cand_d, const int* __restrict__ cand_i,
                  const float* __restrict__ values, float* __restrict__ weighted,
                  float* __restrict__ conf_out) {
    __shared__ float cd[160];
    __shared__ int   ci[160];
    __shared__ float w[5];
    __shared__ int   sel[5];
    __shared__ float conf_s;
    const int row = blockIdx.x;
    const int t = threadIdx.x;
    if (t < 160) {
        cd[t] = cand_d[(size_t)row * 160 + t];
        ci[t] = cand_i[(size_t)row * 160 + t];
    }
    __syncthreads();
    if (t == 0) {
        float bd[5]; int bi[5];
#pragma unroll
        for (int p = 0; p < 5; ++p) { bd[p] = BIGF; bi[p] = 0; }
        for (int c = 0; c < 160; ++c) ins5(bd, bi, cd[c], ci[c]);
        float ww[5]; float s = 0.f;
#pragma unroll
        for (int p = 0; p < 5; ++p) { ww[p] = 1.0f / (bd[p] + EPS_F); s += ww[p]; }
#pragma unroll
        for (int p = 0; p < 5; ++p) { w[p] = ww[p] / s; sel[p] = bi[p]; }
        conf_s = 1.0f / (bd[0] + EPS_F);
    }
    __syncthreads();
    if (t < 128) {
        float acc = 0.f;
#pragma unroll
        for (int p = 0; p < 5; ++p) acc += w[p] * values[(size_t)sel[p] * 128 + t];
        weighted[(size_t)row * 128 + t] = acc;
    }
    if (t == 0) conf_out[row] = conf_s;
}

extern "C" void kernel_launch(void* const* d_in, const int* in_sizes, int n_in,
                              void* d_out, int out_size, void* d_ws, size_t ws_size,
                              hipStream_t stream) {
    const float* query  = (const float*)d_in[0];
    const float* W1     = (const float*)d_in[1];
    const float* b1     = (const float*)d_in[2];
    const float* W2     = (const float*)d_in[3];
    const float* b2     = (const float*)d_in[4];
    const float* W3     = (const float*)d_in[5];
    const float* b3     = (const float*)d_in[6];
    const float* keys   = (const float*)d_in[7];
    const float* values = (const float*)d_in[8];
    const float* D1w    = (const float*)d_in[9];
    const float* D1b    = (const float*)d_in[10];
    const float* D2w    = (const float*)d_in[11];
    const float* D2b    = (const float*)d_in[12];
    const float* D3w    = (const float*)d_in[13];
    const float* D3b    = (const float*)d_in[14];
    // d_in[15] is k; fixed at 5 per setup_inputs (device scalar, cannot host-read under graph capture)
    float* out = (float*)d_out;

    // workspace layout (floats), ~5.4 MB total, buffers reused across phases
    float* ws     = (float*)d_ws;
    float* kk     = ws;                      // 100352
    float* qq     = ws + 100352;             // 1024
    float* cq     = ws + 101376;             // 131072  (reused as `weighted` after dist)
    float* h1     = ws + 232448;             // 524288  (reused as h4)
    float* h2     = ws + 756736;             // 262144  (reused as h3)
    float* cdist  = ws + 1018880;            // 163840
    int*   cidx   = (int*)(ws + 1182720);    // 163840
    float* weighted = cq;
    float* h3 = h2;
    float* h4 = h1;
    float* conf = out + 1024 * 1024;

    rowsq128<<<(NKEYS + 3) / 4, 256, 0, stream>>>(keys, kk, NKEYS);
    sgemm_bias<1><<<dim3(512 / 64, 1024 / 64),  256, 0, stream>>>(query,    W1,  b1,  h1, 1024,  512, 1024);
    sgemm_bias<1><<<dim3(256 / 64, 1024 / 64),  256, 0, stream>>>(h1,       W2,  b2,  h2, 1024,  256,  512);
    sgemm_bias<0><<<dim3(128 / 64, 1024 / 64),  256, 0, stream>>>(h2,       W3,  b3,  cq, 1024,  128,  256);
    rowsq128<<<256, 256, 0, stream>>>(cq, qq, BQ);
    dist_topk<<<dim3(NCHUNK, BQ / 64), 256, 0, stream>>>(cq, keys, kk, qq, cdist, cidx);
    merge_gather<<<BQ, 192, 0, stream>>>(cdist, cidx, values, weighted, conf);
    sgemm_bias<1><<<dim3(256 / 64, 1024 / 64),  256, 0, stream>>>(weighted, D1w, D1b, h3, 1024,  256,  128);
    sgemm_bias<1><<<dim3(512 / 64, 1024 / 64),  256, 0, stream>>>(h3,       D2w, D2b, h4, 1024,  512,  256);
    sgemm_bias<0><<<dim3(1024 / 64, 1024 / 64), 256, 0, stream>>>(h4,       D3w, D3b, out, 1024, 1024,  512);

    (void)in_sizes; (void)n_in; (void)out_size; (void)ws_size;
}

// Round 2
// 548.446 us; speedup vs baseline: 2.3198x; 2.3198x over previous
//
#include <hip/hip_runtime.h>
#include <hip/hip_bf16.h>

#define NKEYS  100000
#define KPAD   100352          // 49 * 2048
#define BQ     1024
#define EPS_F  1e-6f
#define NCHUNK 49
#define CHUNKK 2048            // 32 tiles of 64 keys
#define NCAND  (NCHUNK * 5)    // 245 candidates per row
#define BIGF   1e30f

typedef __attribute__((ext_vector_type(8))) short bf16x8;
typedef __attribute__((ext_vector_type(4))) float f32x4;

// Insert (nd, ni) into ascending sorted 5-list. Fully unrolled -> stays in VGPRs.
__device__ __forceinline__ void ins5(float (&d)[5], int (&ix)[5], float nd, int ni) {
    if (nd < d[4]) {
        d[4] = nd; ix[4] = ni;
#pragma unroll
        for (int p = 4; p > 0; --p) {
            if (d[p] < d[p - 1]) {
                float td = d[p]; d[p] = d[p - 1]; d[p - 1] = td;
                int   ti = ix[p]; ix[p] = ix[p - 1]; ix[p - 1] = ti;
            }
        }
    }
}

// C[M,N] = act(A[M,K] @ W[K,N] + bias). 64x64 tile, 256 threads, 4x4/thread.
template <int RELU>
__global__ __launch_bounds__(256)
void sgemm_bias(const float* __restrict__ A, const float* __restrict__ W,
                const float* __restrict__ bias, float* __restrict__ C,
                int M, int N, int K) {
    __shared__ float As[16][68];
    __shared__ float Bs[16][64];
    const int tid = threadIdx.x;
    const int tx = tid & 15, ty = tid >> 4;
    const int m0 = blockIdx.y * 64, n0 = blockIdx.x * 64;
    float acc[4][4] = {};
    for (int k0 = 0; k0 < K; k0 += 16) {
        {
            int m  = tid >> 2;
            int k4 = (tid & 3) * 4;
            float4 a = *(const float4*)&A[(size_t)(m0 + m) * K + k0 + k4];
            As[k4 + 0][m] = a.x; As[k4 + 1][m] = a.y;
            As[k4 + 2][m] = a.z; As[k4 + 3][m] = a.w;
        }
        {
            int k  = tid >> 4;
            int n4 = (tid & 15) * 4;
            *(float4*)&Bs[k][n4] = *(const float4*)&W[(size_t)(k0 + k) * N + n0 + n4];
        }
        __syncthreads();
#pragma unroll
        for (int kk = 0; kk < 16; ++kk) {
            float4 a4 = *(const float4*)&As[kk][ty * 4];
            float4 b4 = *(const float4*)&Bs[kk][tx * 4];
            float av[4] = {a4.x, a4.y, a4.z, a4.w};
            float bv[4] = {b4.x, b4.y, b4.z, b4.w};
#pragma unroll
            for (int i = 0; i < 4; ++i)
#pragma unroll
                for (int j = 0; j < 4; ++j)
                    acc[i][j] = fmaf(av[i], bv[j], acc[i][j]);
        }
        __syncthreads();
    }
    float4 b4 = *(const float4*)&bias[n0 + tx * 4];
    float bb[4] = {b4.x, b4.y, b4.z, b4.w};
#pragma unroll
    for (int i = 0; i < 4; ++i) {
        float ov[4];
#pragma unroll
        for (int j = 0; j < 4; ++j) {
            float v = acc[i][j] + bb[j];
            if (RELU) v = fmaxf(v, 0.0f);
            ov[j] = v;
        }
        *(float4*)&C[(size_t)(m0 + ty * 4 + i) * N + n0 + tx * 4] =
            make_float4(ov[0], ov[1], ov[2], ov[3]);
    }
}

// out[row] = sum_c X[row][c]^2 (D=128). Rows [nreal, ntot) get BIGF sentinel.
__global__ __launch_bounds__(256)
void rowsq128(const float* __restrict__ X, float* __restrict__ out,
              int nreal, int ntot) {
    int lane = threadIdx.x & 63;
    int row  = blockIdx.x * 4 + (threadIdx.x >> 6);
    if (row >= ntot) return;
    if (row >= nreal) { if (lane == 0) out[row] = BIGF; return; }
    const float* x = X + (size_t)row * 128;
    float a = x[lane], b = x[lane + 64];
    float v = a * a + b * b;
#pragma unroll
    for (int off = 32; off > 0; off >>= 1) v += __shfl_down(v, off, 64);
    if (lane == 0) out[row] = v;
}

// f32 -> bf16 (RNE), n multiple of 4.
__global__ __launch_bounds__(256)
void cvt_bf16_rne(const float* __restrict__ in, ushort* __restrict__ out, int n) {
    int i = (blockIdx.x * 256 + threadIdx.x) * 4;
    if (i >= n) return;
    float4 v = *(const float4*)&in[i];
    __hip_bfloat16 h0 = __float2bfloat16(v.x), h1 = __float2bfloat16(v.y);
    __hip_bfloat16 h2 = __float2bfloat16(v.z), h3 = __float2bfloat16(v.w);
    ushort4 o;
    o.x = *(ushort*)&h0; o.y = *(ushort*)&h1; o.z = *(ushort*)&h2; o.w = *(ushort*)&h3;
    *(ushort4*)&out[i] = o;
}

// bf16-MFMA screening + per-chunk approximate top-5 (score = kk - 2*q.k; qq is
// row-constant so ranking is unaffected). grid = (NCHUNK, BQ/64), block 256.
// Wave w owns query rows m0+16w..+15 (A-frags in registers); 64-key bf16 tiles
// staged in LDS (stride 136 bf16 = 272B; 272 % 128 == 16 -> conflict-free b128).
__global__ __launch_bounds__(256)
void screen_topk(const ushort* __restrict__ qbf, const float* __restrict__ keysf,
                 const float* __restrict__ kk, int* __restrict__ cand_i) {
    __shared__ union __align__(16) SU {
        ushort ks[64][136];                        // 17408 B
        struct { float d[64][80]; int i[64][80]; } m;  // 40960 B
    } S;
    const int tid  = threadIdx.x;
    const int wv   = tid >> 6, ln = tid & 63;
    const int quad = ln >> 4,  l15 = ln & 15;
    const int m0   = blockIdx.y * 64 + wv * 16;
    const int c0   = blockIdx.x * CHUNKK;

    // A fragments: lane holds A[m = m0+l15][k = quad*8 + j + 32s], s=0..3
    bf16x8 afrag[4];
    {
        const ushort* qrow = qbf + (size_t)(m0 + l15) * 128 + quad * 8;
#pragma unroll
        for (int s = 0; s < 4; ++s)
            afrag[s] = *(const bf16x8*)(qrow + 32 * s);
    }

    float t5d[4][5]; int t5i[4][5];   // [C-reg r][5]; reg r -> query row quad*4+r
#pragma unroll
    for (int r = 0; r < 4; ++r)
#pragma unroll
        for (int p = 0; p < 5; ++p) { t5d[r][p] = BIGF; t5i[r][p] = 0; }

    for (int t = 0; t < CHUNKK / 64; ++t) {
        const int n0 = c0 + t * 64;
        __syncthreads();
        // Stage 64 keys x 128 dims: f32 -> trunc-bf16 via v_perm, b128 stores.
#pragma unroll
        for (int it = 0; it < 4; ++it) {
            int idx = tid + it * 256;        // 0..1023
            int r = idx >> 4, u = idx & 15;  // key row, 8-dim unit
            uint4 o = make_uint4(0u, 0u, 0u, 0u);
            if (n0 + r < NKEYS) {
                const float* kp = keysf + (size_t)(n0 + r) * 128 + u * 8;
                float4 a = *(const float4*)kp;
                float4 b = *(const float4*)(kp + 4);
                o.x = __builtin_amdgcn_perm(__float_as_uint(a.y), __float_as_uint(a.x), 0x07060302u);
                o.y = __builtin_amdgcn_perm(__float_as_uint(a.w), __float_as_uint(a.z), 0x07060302u);
                o.z = __builtin_amdgcn_perm(__float_as_uint(b.y), __float_as_uint(b.x), 0x07060302u);
                o.w = __builtin_amdgcn_perm(__float_as_uint(b.w), __float_as_uint(b.z), 0x07060302u);
            }
            *(uint4*)(&S.ks[r][u * 8]) = o;
        }
        __syncthreads();
#pragma unroll
        for (int ct = 0; ct < 4; ++ct) {     // 16-key column tiles
            const int nb = ct * 16;
            f32x4 acc = {0.f, 0.f, 0.f, 0.f};
#pragma unroll
            for (int s = 0; s < 4; ++s) {
                bf16x8 bfr = *(const bf16x8*)(&S.ks[nb + l15][quad * 8 + 32 * s]);
                acc = __builtin_amdgcn_mfma_f32_16x16x32_bf16(afrag[s], bfr, acc, 0, 0, 0);
            }
            const int n = n0 + nb + l15;
            const float kkn = kk[n];         // BIGF for padded keys -> never selected
#pragma unroll
            for (int r = 0; r < 4; ++r) {
                float d = fmaf(-2.0f, acc[r], kkn);
                ins5(t5d[r], t5i[r], d, n);
            }
        }
    }

    __syncthreads();
#pragma unroll
    for (int r = 0; r < 4; ++r)
#pragma unroll
        for (int p = 0; p < 5; ++p) {
            int row = wv * 16 + quad * 4 + r;
            S.m.d[row][l15 * 5 + p] = t5d[r][p];
            S.m.i[row][l15 * 5 + p] = t5i[r][p];
        }
    __syncthreads();
    if (tid < 64) {
        float bd[5]; int bi[5];
#pragma unroll
        for (int p = 0; p < 5; ++p) { bd[p] = BIGF; bi[p] = 0; }
        // offset-read (stride 5*tid mod 80): bank = (21*tid + c) % 32, 21 coprime 32 -> conflict-free
        int c2 = (5 * tid) % 80;
        for (int c = 0; c < 80; ++c) {
            ins5(bd, bi, S.m.d[tid][c2], S.m.i[tid][c2]);
            c2 = (c2 == 79) ? 0 : c2 + 1;
        }
        const int gr = blockIdx.y * 64 + tid;
#pragma unroll
        for (int p = 0; p < 5; ++p)
            cand_i[((size_t)gr * NCHUNK + blockIdx.x) * 5 + p] = bi[p];
    }
}

// Exact f32 re-rank of NCAND candidates/row -> top-5, inverse-distance weights,
// value gather. One block per query row; wave per candidate (coalesced key reads).
__global__ __launch_bounds__(256)
void rerank_gather(const int* __restrict__ cand_i, const float* __restrict__ cq,
                   const float* __restrict__ keysf, const float* __restrict__ qq,
                   const float* __restrict__ kk, const float* __restrict__ values,
                   float* __restrict__ weighted, float* __restrict__ conf_out) {
    __shared__ __align__(16) float qs[128];
    __shared__ float ed[NCAND];
    __shared__ int   ei[NCAND];
    __shared__ float w5[5];
    __shared__ int   s5[5];
    __shared__ float confs;
    const int row = blockIdx.x, tid = threadIdx.x;
    const int wv = tid >> 6, ln = tid & 63;
    if (tid < 128) qs[tid] = cq[(size_t)row * 128 + tid];
    if (tid < NCAND) ei[tid] = cand_i[(size_t)row * NCAND + tid];
    __syncthreads();
    const float2 q2 = *(const float2*)&qs[ln * 2];
    const float qqr = qq[row];
    for (int c = wv; c < NCAND; c += 4) {
        const int idx = ei[c];
        const float2 k2 = *(const float2*)&keysf[(size_t)idx * 128 + ln * 2];
        float dot = q2.x * k2.x + q2.y * k2.y;
#pragma unroll
        for (int off = 32; off > 0; off >>= 1) dot += __shfl_down(dot, off, 64);
        if (ln == 0) ed[c] = qqr + kk[idx] - 2.0f * dot;
    }
    __syncthreads();
    if (tid == 0) {
        float bd[5]; int bi[5];
#pragma unroll
        for (int p = 0; p < 5; ++p) { bd[p] = BIGF; bi[p] = 0; }
        for (int c = 0; c < NCAND; ++c) ins5(bd, bi, ed[c], ei[c]);
        float ww[5]; float s = 0.f;
#pragma unroll
        for (int p = 0; p < 5; ++p) { ww[p] = 1.0f / (bd[p] + EPS_F); s += ww[p]; }
#pragma unroll
        for (int p = 0; p < 5; ++p) { w5[p] = ww[p] / s; s5[p] = bi[p]; }
        confs = 1.0f / (bd[0] + EPS_F);
    }
    __syncthreads();
    if (tid < 128) {
        float acc = 0.f;
#pragma unroll
        for (int p = 0; p < 5; ++p) acc += w5[p] * values[(size_t)s5[p] * 128 + tid];
        weighted[(size_t)row * 128 + tid] = acc;
    }
    if (tid == 0) conf_out[row] = confs;
}

extern "C" void kernel_launch(void* const* d_in, const int* in_sizes, int n_in,
                              void* d_out, int out_size, void* d_ws, size_t ws_size,
                              hipStream_t stream) {
    const float* query  = (const float*)d_in[0];
    const float* W1     = (const float*)d_in[1];
    const float* b1     = (const float*)d_in[2];
    const float* W2     = (const float*)d_in[3];
    const float* b2     = (const float*)d_in[4];
    const float* W3     = (const float*)d_in[5];
    const float* b3     = (const float*)d_in[6];
    const float* keys   = (const float*)d_in[7];
    const float* values = (const float*)d_in[8];
    const float* D1w    = (const float*)d_in[9];
    const float* D1b    = (const float*)d_in[10];
    const float* D2w    = (const float*)d_in[11];
    const float* D2b    = (const float*)d_in[12];
    const float* D3w    = (const float*)d_in[13];
    const float* D3b    = (const float*)d_in[14];
    float* out = (float*)d_out;

    // workspace layout (f32 words), total ~5.34 MB
    float*  ws     = (float*)d_ws;
    float*  kk     = ws;                          // 100352
    float*  qq     = ws + 100352;                 // 1024
    float*  cq     = ws + 101376;                 // 131072
    ushort* qbf    = (ushort*)(ws + 232448);      // 131072 ushorts (65536 words)
    float*  h1     = ws + 297984;                 // 524288
    float*  h2     = ws + 822272;                 // 262144
    int*    cand_i = (int*)(ws + 1084416);        // 1024*245 = 250880
    float*  weighted = cq;   // safe alias: rerank reads its row's cq before writing it
    float*  h3 = h2;
    float*  h4 = h1;
    float*  conf = out + 1024 * 1024;

    rowsq128<<<(KPAD + 3) / 4, 256, 0, stream>>>(keys, kk, NKEYS, KPAD);
    sgemm_bias<1><<<dim3(8, 16),  256, 0, stream>>>(query, W1, b1, h1, 1024, 512, 1024);
    sgemm_bias<1><<<dim3(4, 16),  256, 0, stream>>>(h1,    W2, b2, h2, 1024, 256, 512);
    sgemm_bias<0><<<dim3(2, 16),  256, 0, stream>>>(h2,    W3, b3, cq, 1024, 128, 256);
    rowsq128<<<256, 256, 0, stream>>>(cq, qq, BQ, BQ);
    cvt_bf16_rne<<<128, 256, 0, stream>>>(cq, qbf, BQ * 128);
    screen_topk<<<dim3(NCHUNK, BQ / 64), 256, 0, stream>>>(qbf, keys, kk, cand_i);
    rerank_gather<<<BQ, 256, 0, stream>>>(cand_i, cq, keys, qq, kk, values, weighted, conf);
    sgemm_bias<1><<<dim3(4, 16),  256, 0, stream>>>(weighted, D1w, D1b, h3, 1024, 256, 128);
    sgemm_bias<1><<<dim3(8, 16),  256, 0, stream>>>(h3,       D2w, D2b, h4, 1024, 512, 256);
    sgemm_bias<0><<<dim3(16, 16), 256, 0, stream>>>(h4,       D3w, D3b, out, 1024, 1024, 512);

    (void)in_sizes; (void)n_in; (void)out_size; (void)ws_size;
}

// Round 3
// 509.765 us; speedup vs baseline: 2.4958x; 1.0759x over previous
//
#include <hip/hip_runtime.h>
#include <hip/hip_bf16.h>

#define NKEYS  100000
#define KPAD   100352          // 98 chunks * 1024; 1568 64-key tiles
#define BQ     1024
#define EPS_F  1e-6f
#define NCH    98
#define CHK    1024            // keys per chunk (16 tiles of 64)
#define NCAND  (NCH * 5)       // 490 candidates per row
#define BIGF   1e30f

typedef __attribute__((ext_vector_type(8))) short bf16x8;
typedef __attribute__((ext_vector_type(4))) float f32x4;

__device__ __forceinline__ void gl_lds16(const uint4* g, uint4* l) {
    __builtin_amdgcn_global_load_lds((const __attribute__((address_space(1))) void*)g,
                                     (__attribute__((address_space(3))) void*)l, 16, 0, 0);
}

// Insert (nd, ni) into ascending sorted 5-list (register-resident when unrolled).
__device__ __forceinline__ void ins5(float (&d)[5], int (&ix)[5], float nd, int ni) {
    if (nd < d[4]) {
        d[4] = nd; ix[4] = ni;
#pragma unroll
        for (int p = 4; p > 0; --p) {
            if (d[p] < d[p - 1]) {
                float td = d[p]; d[p] = d[p - 1]; d[p - 1] = td;
                int   ti = ix[p]; ix[p] = ix[p - 1]; ix[p - 1] = ti;
            }
        }
    }
}

// ---------- one-time key preprocessing: bf16 image (MFMA-fragment-major) + kk ----------
// Image layout per 64-key tile: 256 uint4 chunks; chunk j = ((ct*4+s)*4+quad)*16+l15
// holds key row (ct*16+l15), dims [s*32+quad*8 .. +7] as 8 bf16. Then a B-frag
// ds_read_b128 for (ct,s) by lane ln reads chunk (ct*4+s)*64+ln: consecutive lanes ->
// consecutive 16B -> conflict-free, and global_load_lds staging is linear.
__global__ __launch_bounds__(256)
void cvt_keys(const float* __restrict__ keys, uint4* __restrict__ img,
              float* __restrict__ kk) {
    const int tid = threadIdx.x;
    const int r = tid >> 2, s = tid & 3;          // r: key row in tile, s: 32-dim slab
    const int tile = blockIdx.x;
    const int n = tile * 64 + r;
    const int ct = r >> 4, l15 = r & 15;
    const bool live = (n < NKEYS);
    const float* kp = keys + (size_t)n * 128 + s * 32;
    float ss = 0.f;
    uint4 out[4];
#pragma unroll
    for (int q = 0; q < 4; ++q) {
        float4 a = make_float4(0.f, 0.f, 0.f, 0.f), b = a;
        if (live) { a = *(const float4*)(kp + q * 8); b = *(const float4*)(kp + q * 8 + 4); }
        ss += a.x * a.x + a.y * a.y + a.z * a.z + a.w * a.w
            + b.x * b.x + b.y * b.y + b.z * b.z + b.w * b.w;
        ushort h[8];
        float v[8] = {a.x, a.y, a.z, a.w, b.x, b.y, b.z, b.w};
#pragma unroll
        for (int j = 0; j < 8; ++j) {
            __hip_bfloat16 t = __float2bfloat16(v[j]);
            h[j] = *(ushort*)&t;
        }
        out[q] = make_uint4((uint)h[0] | ((uint)h[1] << 16), (uint)h[2] | ((uint)h[3] << 16),
                            (uint)h[4] | ((uint)h[5] << 16), (uint)h[6] | ((uint)h[7] << 16));
    }
    ss += __shfl_xor(ss, 1, 64);
    ss += __shfl_xor(ss, 2, 64);
    if (s == 0) kk[n] = live ? ss : BIGF;
#pragma unroll
    for (int q = 0; q < 4; ++q)
        img[(size_t)tile * 256 + ((ct * 4 + s) * 4 + q) * 16 + l15] = out[q];
}

// ---------- split-K f32 GEMM: P[z] = A[:, kb:kb+ks] @ W[kb:kb+ks, :] ----------
__global__ __launch_bounds__(256)
void sgemm_part(const float* __restrict__ A, const float* __restrict__ W,
                float* __restrict__ P, int M, int N, int K, int kslice) {
    __shared__ float As[16][68];
    __shared__ float Bs[16][64];
    const int tid = threadIdx.x;
    const int tx = tid & 15, ty = tid >> 4;
    const int m0 = blockIdx.y * 64, n0 = blockIdx.x * 64;
    const int kb = blockIdx.z * kslice, ke = kb + kslice;
    float acc[4][4] = {};
    for (int k0 = kb; k0 < ke; k0 += 16) {
        {
            int m = tid >> 2, k4 = (tid & 3) * 4;
            float4 a = *(const float4*)&A[(size_t)(m0 + m) * K + k0 + k4];
            As[k4 + 0][m] = a.x; As[k4 + 1][m] = a.y;
            As[k4 + 2][m] = a.z; As[k4 + 3][m] = a.w;
        }
        {
            int k = tid >> 4, n4 = (tid & 15) * 4;
            *(float4*)&Bs[k][n4] = *(const float4*)&W[(size_t)(k0 + k) * N + n0 + n4];
        }
        __syncthreads();
#pragma unroll
        for (int kkk = 0; kkk < 16; ++kkk) {
            float4 a4 = *(const float4*)&As[kkk][ty * 4];
            float4 b4 = *(const float4*)&Bs[kkk][tx * 4];
            float av[4] = {a4.x, a4.y, a4.z, a4.w};
            float bv[4] = {b4.x, b4.y, b4.z, b4.w};
#pragma unroll
            for (int i = 0; i < 4; ++i)
#pragma unroll
                for (int j = 0; j < 4; ++j)
                    acc[i][j] = fmaf(av[i], bv[j], acc[i][j]);
        }
        __syncthreads();
    }
    P += (size_t)blockIdx.z * M * N;
#pragma unroll
    for (int i = 0; i < 4; ++i)
        *(float4*)&P[(size_t)(m0 + ty * 4 + i) * N + n0 + tx * 4] =
            make_float4(acc[i][0], acc[i][1], acc[i][2], acc[i][3]);
}

// C = act(sum_z P[z] + bias)
template <int RELU>
__global__ __launch_bounds__(256)
void reduce_bias(const float* __restrict__ P, const float* __restrict__ bias,
                 float* __restrict__ C, int MN, int N, int nP) {
    int i4 = (blockIdx.x * 256 + threadIdx.x) * 4;
    if (i4 >= MN) return;
    float4 s = *(const float4*)&P[i4];
    for (int p = 1; p < nP; ++p) {
        float4 v = *(const float4*)&P[(size_t)p * MN + i4];
        s.x += v.x; s.y += v.y; s.z += v.z; s.w += v.w;
    }
    float4 b = *(const float4*)&bias[i4 % N];
    s.x += b.x; s.y += b.y; s.z += b.z; s.w += b.w;
    if (RELU) {
        s.x = fmaxf(s.x, 0.f); s.y = fmaxf(s.y, 0.f);
        s.z = fmaxf(s.z, 0.f); s.w = fmaxf(s.w, 0.f);
    }
    *(float4*)&C[i4] = s;
}

// out[row] = sum_c X[row][c]^2 (D=128 rows)
__global__ __launch_bounds__(256)
void rowsq128(const float* __restrict__ X, float* __restrict__ out, int nrows) {
    int lane = threadIdx.x & 63;
    int row  = blockIdx.x * 4 + (threadIdx.x >> 6);
    if (row >= nrows) return;
    const float* x = X + (size_t)row * 128;
    float a = x[lane], b = x[lane + 64];
    float v = a * a + b * b;
#pragma unroll
    for (int off = 32; off > 0; off >>= 1) v += __shfl_down(v, off, 64);
    if (lane == 0) out[row] = v;
}

// f32 -> bf16 RNE (queries), n multiple of 4
__global__ __launch_bounds__(256)
void cvt_bf16_rne(const float* __restrict__ in, ushort* __restrict__ out, int n) {
    int i = (blockIdx.x * 256 + threadIdx.x) * 4;
    if (i >= n) return;
    float4 v = *(const float4*)&in[i];
    __hip_bfloat16 h0 = __float2bfloat16(v.x), h1 = __float2bfloat16(v.y);
    __hip_bfloat16 h2 = __float2bfloat16(v.z), h3 = __float2bfloat16(v.w);
    ushort4 o;
    o.x = *(ushort*)&h0; o.y = *(ushort*)&h1; o.z = *(ushort*)&h2; o.w = *(ushort*)&h3;
    *(ushort4*)&out[i] = o;
}

// ---------- bf16-MFMA screening: per-chunk approx top-5 (score = kk - 2 q.k) ----------
// grid (NCH, BQ/128), block 256 = 4 waves x 32 query rows. Key tiles staged from the
// pre-swizzled image via double-buffered global_load_lds; per-row top-5 merged across
// the 16 lanes of each quad by shfl_xor butterfly. Exact-recall per chunk; bf16 error
// << 5th/6th-neighbor gap, and rerank recomputes exactly.
__global__ __launch_bounds__(256, 3)
void screen_topk(const ushort* __restrict__ qbf, const uint4* __restrict__ img,
                 const float* __restrict__ kk, int* __restrict__ cand_i) {
    __shared__ uint4 buf[2][1024];   // 2 x 16 KB key tiles
    __shared__ float kks[CHK];       // 4 KB chunk kk
    const int tid = threadIdx.x;
    const int wv = tid >> 6, ln = tid & 63;
    const int quad = ln >> 4, l15 = ln & 15;
    const int m0 = blockIdx.y * 128 + wv * 32;
    const int c0 = blockIdx.x * CHK;
    const int t0 = c0 >> 6;          // global 64-key tile index base

    bf16x8 afA[4], afB[4];
    {
        const ushort* qa = qbf + (size_t)(m0 + l15) * 128 + quad * 8;
#pragma unroll
        for (int s = 0; s < 4; ++s) {
            afA[s] = *(const bf16x8*)(qa + 32 * s);
            afB[s] = *(const bf16x8*)(qa + 16 * 128 + 32 * s);
        }
    }
    *(float4*)&kks[tid * 4] = *(const float4*)&kk[c0 + tid * 4];

    float dA[4][5], dB[4][5]; int iA[4][5], iB[4][5];
#pragma unroll
    for (int r = 0; r < 4; ++r)
#pragma unroll
        for (int p = 0; p < 5; ++p) {
            dA[r][p] = BIGF; iA[r][p] = 0;
            dB[r][p] = BIGF; iB[r][p] = 0;
        }

    // stage tile 0
#pragma unroll
    for (int it = 0; it < 4; ++it)
        gl_lds16(&img[(size_t)t0 * 256 + it * 256 + wv * 64 + ln], &buf[0][it * 256 + wv * 64]);
    __syncthreads();

    for (int t = 0; t < CHK / 64; ++t) {
        const int b = t & 1;
        if (t + 1 < CHK / 64) {
#pragma unroll
            for (int it = 0; it < 4; ++it)
                gl_lds16(&img[(size_t)(t0 + t + 1) * 256 + it * 256 + wv * 64 + ln],
                         &buf[b ^ 1][it * 256 + wv * 64]);
        }
#pragma unroll
        for (int ct = 0; ct < 4; ++ct) {
            f32x4 a0 = {0.f, 0.f, 0.f, 0.f}, a1 = a0;
#pragma unroll
            for (int s = 0; s < 4; ++s) {
                bf16x8 bfr = *(const bf16x8*)&buf[b][(ct * 4 + s) * 64 + ln];
                a0 = __builtin_amdgcn_mfma_f32_16x16x32_bf16(afA[s], bfr, a0, 0, 0, 0);
                a1 = __builtin_amdgcn_mfma_f32_16x16x32_bf16(afB[s], bfr, a1, 0, 0, 0);
            }
            const int nl = t * 64 + ct * 16 + l15;
            const float kkn = kks[nl];
            const int n = c0 + nl;
#pragma unroll
            for (int r = 0; r < 4; ++r) {
                ins5(dA[r], iA[r], fmaf(-2.0f, a0[r], kkn), n);
                ins5(dB[r], iB[r], fmaf(-2.0f, a1[r], kkn), n);
            }
        }
        __syncthreads();   // waves done reading buf[b]; staged loads to buf[b^1] drained
    }

    // butterfly merge across the 16 lanes of each quad, then lane l15==0 writes
#pragma unroll
    for (int set = 0; set < 2; ++set) {
#pragma unroll
        for (int r = 0; r < 4; ++r) {
            float d[5]; int ix[5];
#pragma unroll
            for (int p = 0; p < 5; ++p) {
                d[p]  = set ? dB[r][p] : dA[r][p];
                ix[p] = set ? iB[r][p] : iA[r][p];
            }
#pragma unroll
            for (int m = 1; m <= 8; m <<= 1) {
                float od[5]; int oi[5];
#pragma unroll
                for (int p = 0; p < 5; ++p) {
                    od[p] = __shfl_xor(d[p], m, 64);
                    oi[p] = __shfl_xor(ix[p], m, 64);
                }
#pragma unroll
                for (int p = 0; p < 5; ++p) ins5(d, ix, od[p], oi[p]);
            }
            if (l15 == 0) {
                const int row = m0 + set * 16 + quad * 4 + r;
#pragma unroll
                for (int p = 0; p < 5; ++p)
                    cand_i[((size_t)row * NCH + blockIdx.x) * 5 + p] = ix[p];
            }
        }
    }
}

// ---------- exact f32 re-rank of 490 candidates/row + weighted value gather ----------
__global__ __launch_bounds__(256)
void rerank_gather(const int* __restrict__ cand_i, const float* __restrict__ cq,
                   const float* __restrict__ keysf, const float* __restrict__ qq,
                   const float* __restrict__ kk, const float* __restrict__ values,
                   float* __restrict__ weighted, float* __restrict__ conf_out) {
    __shared__ __align__(16) float qs[128];
    __shared__ float ed[NCAND];
    __shared__ int   ei[NCAND];
    __shared__ float w5[5];
    __shared__ int   s5[5];
    __shared__ float confs;
    const int row = blockIdx.x, tid = threadIdx.x;
    const int wv = tid >> 6, ln = tid & 63;
    if (tid < 128) qs[tid] = cq[(size_t)row * 128 + tid];
    for (int c = tid; c < NCAND; c += 256) ei[c] = cand_i[(size_t)row * NCAND + c];
    __syncthreads();
    const float2 q2 = *(const float2*)&qs[ln * 2];
    const float qqr = qq[row];
    for (int c = wv; c < NCAND; c += 4) {
        const int idx = ei[c];
        const float2 k2 = *(const float2*)&keysf[(size_t)idx * 128 + ln * 2];
        float dot = q2.x * k2.x + q2.y * k2.y;
#pragma unroll
        for (int off = 32; off > 0; off >>= 1) dot += __shfl_down(dot, off, 64);
        if (ln == 0) ed[c] = qqr + kk[idx] - 2.0f * dot;
    }
    __syncthreads();
    if (wv == 0) {   // wave-parallel final top-5
        float bd[5]; int bi[5];
#pragma unroll
        for (int p = 0; p < 5; ++p) { bd[p] = BIGF; bi[p] = 0; }
        for (int c = ln; c < NCAND; c += 64) ins5(bd, bi, ed[c], ei[c]);
#pragma unroll
        for (int m = 1; m <= 32; m <<= 1) {
            float od[5]; int oi[5];
#pragma unroll
            for (int p = 0; p < 5; ++p) {
                od[p] = __shfl_xor(bd[p], m, 64);
                oi[p] = __shfl_xor(bi[p], m, 64);
            }
#pragma unroll
            for (int p = 0; p < 5; ++p) ins5(bd, bi, od[p], oi[p]);
        }
        if (ln == 0) {
            float ww[5]; float s = 0.f;
#pragma unroll
            for (int p = 0; p < 5; ++p) { ww[p] = 1.0f / (bd[p] + EPS_F); s += ww[p]; }
#pragma unroll
            for (int p = 0; p < 5; ++p) { w5[p] = ww[p] / s; s5[p] = bi[p]; }
            confs = 1.0f / (bd[0] + EPS_F);
        }
    }
    __syncthreads();
    if (tid < 128) {
        float acc = 0.f;
#pragma unroll
        for (int p = 0; p < 5; ++p) acc += w5[p] * values[(size_t)s5[p] * 128 + tid];
        weighted[(size_t)row * 128 + tid] = acc;
    }
    if (tid == 0) conf_out[row] = confs;
}

extern "C" void kernel_launch(void* const* d_in, const int* in_sizes, int n_in,
                              void* d_out, int out_size, void* d_ws, size_t ws_size,
                              hipStream_t stream) {
    const float* query  = (const float*)d_in[0];
    const float* W1     = (const float*)d_in[1];
    const float* b1     = (const float*)d_in[2];
    const float* W2     = (const float*)d_in[3];
    const float* b2     = (const float*)d_in[4];
    const float* W3     = (const float*)d_in[5];
    const float* b3     = (const float*)d_in[6];
    const float* keys   = (const float*)d_in[7];
    const float* values = (const float*)d_in[8];
    const float* D1w    = (const float*)d_in[9];
    const float* D1b    = (const float*)d_in[10];
    const float* D2w    = (const float*)d_in[11];
    const float* D2b    = (const float*)d_in[12];
    const float* D3w    = (const float*)d_in[13];
    const float* D3b    = (const float*)d_in[14];
    float* out = (float*)d_out;

    // workspace layout (f32 words), ~38.4 MB total
    float*  ws   = (float*)d_ws;
    float*  kk   = ws;                       // 100352
    float*  qq   = ws + 100352;              // 1024
    float*  cq   = ws + 101376;              // 131072
    ushort* qbf  = (ushort*)(ws + 232448);   // 131072 ushorts
    float*  h1   = ws + 297984;              // 524288
    float*  h2   = ws + 822272;              // 262144
    float*  part = ws + 1084416;             // 2097152 (8 MB; cand_i aliases base)
    uint4*  img  = (uint4*)(ws + 3181568);   // 6422528 words = 25.7 MB bf16 key image
    int*    cand = (int*)part;               // 1024*490 ints; dead before D1 gemm reuses part
    float*  weighted = cq;                   // rerank reads its row's cq before overwrite
    float*  h3 = h2;
    float*  h4 = h1;
    float*  conf = out + 1024 * 1024;

    cvt_keys<<<KPAD / 64, 256, 0, stream>>>(keys, img, kk);
    // compress MLP (f32, split-K)
    sgemm_part<<<dim3(8, 16, 4),  256, 0, stream>>>(query, W1, part, 1024, 512, 1024, 256);
    reduce_bias<1><<<512, 256, 0, stream>>>(part, b1, h1, 1024 * 512, 512, 4);
    sgemm_part<<<dim3(4, 16, 8),  256, 0, stream>>>(h1, W2, part, 1024, 256, 512, 64);
    reduce_bias<1><<<256, 256, 0, stream>>>(part, b2, h2, 1024 * 256, 256, 8);
    sgemm_part<<<dim3(2, 16, 8),  256, 0, stream>>>(h2, W3, part, 1024, 128, 256, 32);
    reduce_bias<0><<<128, 256, 0, stream>>>(part, b3, cq, 1024 * 128, 128, 8);
    rowsq128<<<256, 256, 0, stream>>>(cq, qq, BQ);
    cvt_bf16_rne<<<128, 256, 0, stream>>>(cq, qbf, BQ * 128);
    // retrieval
    screen_topk<<<dim3(NCH, BQ / 128), 256, 0, stream>>>(qbf, img, kk, cand);
    rerank_gather<<<BQ, 256, 0, stream>>>(cand, cq, keys, qq, kk, values, weighted, conf);
    // decompress MLP (f32, split-K)
    sgemm_part<<<dim3(4, 16, 4),  256, 0, stream>>>(weighted, D1w, part, 1024, 256, 128, 32);
    reduce_bias<1><<<256, 256, 0, stream>>>(part, D1b, h3, 1024 * 256, 256, 4);
    sgemm_part<<<dim3(8, 16, 4),  256, 0, stream>>>(h3, D2w, part, 1024, 512, 256, 64);
    reduce_bias<1><<<512, 256, 0, stream>>>(part, D2b, h4, 1024 * 512, 512, 4);
    sgemm_part<<<dim3(16, 16, 2), 256, 0, stream>>>(h4, D3w, part, 1024, 1024, 512, 256);
    reduce_bias<0><<<1024, 256, 0, stream>>>(part, D3b, out, 1024 * 1024, 1024, 2);

    (void)in_sizes; (void)n_in; (void)out_size; (void)ws_size;
}

// Round 4
// 349.197 us; speedup vs baseline: 3.6434x; 1.4598x over previous
//
#include <hip/hip_runtime.h>
#include <hip/hip_bf16.h>

#define NKEYS  100000
#define NCH    92
#define CHK    1088            // 17 tiles of 64 keys
#define TPC    17              // tiles per chunk
#define KPAD   (NCH * CHK)     // 100096
#define NTILE  (KPAD / 64)     // 1564
#define BQ     1024
#define EPS_F  1e-6f
#define NCAND  (NCH * 4)       // 368 candidates per row
#define BIGF   1e30f

typedef __attribute__((ext_vector_type(8))) short bf16x8;
typedef __attribute__((ext_vector_type(4))) float f32x4;

__device__ __forceinline__ void gl_lds16(const uint4* g, uint4* l) {
    __builtin_amdgcn_global_load_lds((const __attribute__((address_space(1))) void*)g,
                                     (__attribute__((address_space(3))) void*)l, 16, 0, 0);
}
__device__ __forceinline__ unsigned umn(unsigned a, unsigned b) { return a < b ? a : b; }
__device__ __forceinline__ unsigned umx(unsigned a, unsigned b) { return a > b ? a : b; }

// branchless insert into ascending sorted top-3 of packed uints (5 min/max)
__device__ __forceinline__ void ins3u(unsigned (&m)[3], unsigned u) {
    unsigned v1 = umn(m[2], u);
    m[2] = umx(m[1], v1);
    unsigned v2 = umn(m[1], v1);
    m[1] = umx(m[0], v2);
    m[0] = umn(m[0], v2);
}
// branchless insert into ascending sorted top-4 (7 min/max)
__device__ __forceinline__ void ins4u(unsigned (&m)[4], unsigned u) {
    unsigned v1 = umn(m[3], u);
    m[3] = umx(m[2], v1);
    unsigned v2 = umn(m[2], v1);
    m[2] = umx(m[1], v2);
    unsigned v3 = umn(m[1], v2);
    m[1] = umx(m[0], v3);
    m[0] = umn(m[0], v3);
}

// f32 (dist,idx) sorted top-5 insert (rerank only — off the hot path)
__device__ __forceinline__ void ins5(float (&d)[5], int (&ix)[5], float nd, int ni) {
    if (nd < d[4]) {
        d[4] = nd; ix[4] = ni;
#pragma unroll
        for (int p = 4; p > 0; --p) {
            if (d[p] < d[p - 1]) {
                float td = d[p]; d[p] = d[p - 1]; d[p - 1] = td;
                int   ti = ix[p]; ix[p] = ix[p - 1]; ix[p - 1] = ti;
            }
        }
    }
}

// ---------- one-time key preprocessing: fragment-major bf16 image + kk + (-kk/2) ----------
// Per 64-key tile: 1024 uint4; chunk ((ct*4+s)*4+quad)*16+l15 holds key (ct*16+l15),
// dims [s*32+quad*8 .. +7]. B-frag ds_read_b128 by lane ln hits chunk (ct*4+s)*64+ln:
// consecutive lanes -> consecutive 16B -> conflict-free; staging is linear.
__global__ __launch_bounds__(256)
void cvt_keys(const float* __restrict__ keys, uint4* __restrict__ img,
              float* __restrict__ kk, float* __restrict__ khalf) {
    const int tid = threadIdx.x;
    const int r = tid >> 2, s = tid & 3;
    const int tile = blockIdx.x;
    const int n = tile * 64 + r;
    const int ct = r >> 4, l15 = r & 15;
    const bool live = (n < NKEYS);
    const float* kp = keys + (size_t)n * 128 + s * 32;
    float ss = 0.f;
    uint4 out[4];
#pragma unroll
    for (int q = 0; q < 4; ++q) {
        float4 a = make_float4(0.f, 0.f, 0.f, 0.f), b = a;
        if (live) { a = *(const float4*)(kp + q * 8); b = *(const float4*)(kp + q * 8 + 4); }
        ss += a.x * a.x + a.y * a.y + a.z * a.z + a.w * a.w
            + b.x * b.x + b.y * b.y + b.z * b.z + b.w * b.w;
        float v[8] = {a.x, a.y, a.z, a.w, b.x, b.y, b.z, b.w};
        ushort h[8];
#pragma unroll
        for (int j = 0; j < 8; ++j) {
            __hip_bfloat16 t = __float2bfloat16(v[j]);
            h[j] = *(ushort*)&t;
        }
        out[q] = make_uint4((uint)h[0] | ((uint)h[1] << 16), (uint)h[2] | ((uint)h[3] << 16),
                            (uint)h[4] | ((uint)h[5] << 16), (uint)h[6] | ((uint)h[7] << 16));
    }
    ss += __shfl_xor(ss, 1, 64);
    ss += __shfl_xor(ss, 2, 64);
    if (s == 0) {
        kk[n]    = live ? ss : BIGF;
        khalf[n] = live ? -0.5f * ss : -BIGF;
    }
#pragma unroll
    for (int q = 0; q < 4; ++q)
        img[(size_t)tile * 1024 + ((ct * 4 + s) * 4 + q) * 16 + l15] = out[q];  // stride 1024 (round-3 bug: 256)
}

// ---------- split-K f32 GEMM + reduce (compress MLP must stay f32-exact) ----------
__global__ __launch_bounds__(256)
void sgemm_part(const float* __restrict__ A, const float* __restrict__ W,
                float* __restrict__ P, int M, int N, int K, int kslice) {
    __shared__ float As[16][68];
    __shared__ float Bs[16][64];
    const int tid = threadIdx.x;
    const int tx = tid & 15, ty = tid >> 4;
    const int m0 = blockIdx.y * 64, n0 = blockIdx.x * 64;
    const int kb = blockIdx.z * kslice, ke = kb + kslice;
    float acc[4][4] = {};
    for (int k0 = kb; k0 < ke; k0 += 16) {
        {
            int m = tid >> 2, k4 = (tid & 3) * 4;
            float4 a = *(const float4*)&A[(size_t)(m0 + m) * K + k0 + k4];
            As[k4 + 0][m] = a.x; As[k4 + 1][m] = a.y;
            As[k4 + 2][m] = a.z; As[k4 + 3][m] = a.w;
        }
        {
            int k = tid >> 4, n4 = (tid & 15) * 4;
            *(float4*)&Bs[k][n4] = *(const float4*)&W[(size_t)(k0 + k) * N + n0 + n4];
        }
        __syncthreads();
#pragma unroll
        for (int kkk = 0; kkk < 16; ++kkk) {
            float4 a4 = *(const float4*)&As[kkk][ty * 4];
            float4 b4 = *(const float4*)&Bs[kkk][tx * 4];
            float av[4] = {a4.x, a4.y, a4.z, a4.w};
            float bv[4] = {b4.x, b4.y, b4.z, b4.w};
#pragma unroll
            for (int i = 0; i < 4; ++i)
#pragma unroll
                for (int j = 0; j < 4; ++j)
                    acc[i][j] = fmaf(av[i], bv[j], acc[i][j]);
        }
        __syncthreads();
    }
    P += (size_t)blockIdx.z * M * N;
#pragma unroll
    for (int i = 0; i < 4; ++i)
        *(float4*)&P[(size_t)(m0 + ty * 4 + i) * N + n0 + tx * 4] =
            make_float4(acc[i][0], acc[i][1], acc[i][2], acc[i][3]);
}

template <int RELU>
__global__ __launch_bounds__(256)
void reduce_bias(const float* __restrict__ P, const float* __restrict__ bias,
                 float* __restrict__ C, int MN, int N, int nP) {
    int i4 = (blockIdx.x * 256 + threadIdx.x) * 4;
    if (i4 >= MN) return;
    float4 s = *(const float4*)&P[i4];
    for (int p = 1; p < nP; ++p) {
        float4 v = *(const float4*)&P[(size_t)p * MN + i4];
        s.x += v.x; s.y += v.y; s.z += v.z; s.w += v.w;
    }
    float4 b = *(const float4*)&bias[i4 % N];
    s.x += b.x; s.y += b.y; s.z += b.z; s.w += b.w;
    if (RELU) {
        s.x = fmaxf(s.x, 0.f); s.y = fmaxf(s.y, 0.f);
        s.z = fmaxf(s.z, 0.f); s.w = fmaxf(s.w, 0.f);
    }
    *(float4*)&C[i4] = s;
}

__global__ __launch_bounds__(256)
void rowsq128(const float* __restrict__ X, float* __restrict__ out, int nrows) {
    int lane = threadIdx.x & 63;
    int row  = blockIdx.x * 4 + (threadIdx.x >> 6);
    if (row >= nrows) return;
    const float* x = X + (size_t)row * 128;
    float a = x[lane], b = x[lane + 64];
    float v = a * a + b * b;
#pragma unroll
    for (int off = 32; off > 0; off >>= 1) v += __shfl_down(v, off, 64);
    if (lane == 0) out[row] = v;
}

__global__ __launch_bounds__(256)
void cvt_bf16_rne(const float* __restrict__ in, ushort* __restrict__ out, int n) {
    int i = (blockIdx.x * 256 + threadIdx.x) * 4;
    if (i >= n) return;
    float4 v = *(const float4*)&in[i];
    __hip_bfloat16 h0 = __float2bfloat16(v.x), h1 = __float2bfloat16(v.y);
    __hip_bfloat16 h2 = __float2bfloat16(v.z), h3 = __float2bfloat16(v.w);
    ushort4 o;
    o.x = *(ushort*)&h0; o.y = *(ushort*)&h1; o.z = *(ushort*)&h2; o.w = *(ushort*)&h3;
    *(ushort4*)&out[i] = o;
}

// ---------- weight -> fragment-major bf16 image (for decompress MFMA GEMMs) ----------
// Per (64-col, 64-k) panel: 512 uint4; chunk ((ct*2+s)*4+quad)*16+l15 holds
// col ct*16+l15, k s*32+quad*8..+7. Panel blob at (ctile*(K/64)+p)*512.
__global__ __launch_bounds__(256)
void cvt_wT(const float* __restrict__ W, uint4* __restrict__ Wimg, int K, int N) {
    const int ctile = blockIdx.x, p = blockIdx.y;
    const int npan = K >> 6;
#pragma unroll
    for (int it = 0; it < 2; ++it) {
        int c = it * 256 + threadIdx.x;
        int l15 = c & 15, quad = (c >> 4) & 3, s = (c >> 6) & 1, ct = c >> 7;
        int n = ctile * 64 + ct * 16 + l15;
        int k = p * 64 + s * 32 + quad * 8;
        ushort h[8];
#pragma unroll
        for (int j = 0; j < 8; ++j) {
            __hip_bfloat16 t = __float2bfloat16(W[(size_t)(k + j) * N + n]);
            h[j] = *(ushort*)&t;
        }
        Wimg[((size_t)ctile * npan + p) * 512 + c] =
            make_uint4((uint)h[0] | ((uint)h[1] << 16), (uint)h[2] | ((uint)h[3] << 16),
                       (uint)h[4] | ((uint)h[5] << 16), (uint)h[6] | ((uint)h[7] << 16));
    }
}

// ---------- bf16-MFMA screening with packed-uint branchless top-3 scan ----------
// acc init = -kk/2 -> acc_final = q.k - kk/2 = -d/2 (all negative; uint order = ascending d).
// Pack: (bits & 0xFFFFF800) | nl (11-bit local key idx); per-lane sorted top-3 (5 min/max);
// chunk merge: expand to top-4, 4-step shfl_xor butterfly over l15 -> 4 cands/(row,chunk).
// Coverage: row-rank-j (j<=5) lost needs 3 of ranks1-4 in same lane-stream (~1e-9) or all
// 4 in same chunk (~1e-8). Exact f32 rerank downstream keeps final selection exact.
__global__ __launch_bounds__(256, 3)
void screen_topk(const ushort* __restrict__ qbf, const uint4* __restrict__ img,
                 const float* __restrict__ khalf, int* __restrict__ cand_i) {
    __shared__ uint4 buf[2][1024];   // 2 x 16 KB key tiles
    __shared__ float kls[CHK];       // -kk/2 for chunk
    const int tid = threadIdx.x;
    const int wv = tid >> 6, ln = tid & 63;
    const int quad = ln >> 4, l15 = ln & 15;
    const int m0 = blockIdx.y * 128 + wv * 32;
    const int c0 = blockIdx.x * CHK;
    const int t0 = blockIdx.x * TPC;

    bf16x8 afA[4], afB[4];
    {
        const ushort* qa = qbf + (size_t)(m0 + l15) * 128 + quad * 8;
#pragma unroll
        for (int s = 0; s < 4; ++s) {
            afA[s] = *(const bf16x8*)(qa + 32 * s);
            afB[s] = *(const bf16x8*)(qa + 16 * 128 + 32 * s);
        }
    }
    for (int i = tid; i < CHK; i += 256) kls[i] = khalf[c0 + i];

    unsigned mA[4][3], mB[4][3];
#pragma unroll
    for (int r = 0; r < 4; ++r)
#pragma unroll
        for (int p = 0; p < 3; ++p) { mA[r][p] = 0xFFFFFFFFu; mB[r][p] = 0xFFFFFFFFu; }

#pragma unroll
    for (int it = 0; it < 4; ++it)
        gl_lds16(&img[(size_t)t0 * 1024 + it * 256 + wv * 64 + ln], &buf[0][it * 256 + wv * 64]);
    __syncthreads();

    for (int t = 0; t < TPC; ++t) {
        const int b = t & 1;
        if (t + 1 < TPC) {
#pragma unroll
            for (int it = 0; it < 4; ++it)
                gl_lds16(&img[(size_t)(t0 + t + 1) * 1024 + it * 256 + wv * 64 + ln],
                         &buf[b ^ 1][it * 256 + wv * 64]);
        }
#pragma unroll
        for (int ct = 0; ct < 4; ++ct) {
            const int nl = t * 64 + ct * 16 + l15;   // local key idx, matches C col l15
            const float kh = kls[nl];
            f32x4 a0 = {kh, kh, kh, kh}, a1 = {kh, kh, kh, kh};
#pragma unroll
            for (int s = 0; s < 4; ++s) {
                bf16x8 bfr = *(const bf16x8*)&buf[b][(ct * 4 + s) * 64 + ln];
                a0 = __builtin_amdgcn_mfma_f32_16x16x32_bf16(afA[s], bfr, a0, 0, 0, 0);
                a1 = __builtin_amdgcn_mfma_f32_16x16x32_bf16(afB[s], bfr, a1, 0, 0, 0);
            }
#pragma unroll
            for (int r = 0; r < 4; ++r) {
                ins3u(mA[r], (__float_as_uint(a0[r]) & 0xFFFFF800u) | (unsigned)nl);
                ins3u(mB[r], (__float_as_uint(a1[r]) & 0xFFFFF800u) | (unsigned)nl);
            }
        }
        __syncthreads();
    }

    // merge: per (set,r) expand to top-4 and butterfly across the quad's 16 lanes
#pragma unroll
    for (int set = 0; set < 2; ++set) {
#pragma unroll
        for (int r = 0; r < 4; ++r) {
            unsigned m[4];
#pragma unroll
            for (int p = 0; p < 3; ++p) m[p] = set ? mB[r][p] : mA[r][p];
            m[3] = 0xFFFFFFFFu;
#pragma unroll
            for (int st = 1; st <= 8; st <<= 1) {
                unsigned o[4];
#pragma unroll
                for (int p = 0; p < 4; ++p) o[p] = (unsigned)__shfl_xor((int)m[p], st, 64);
#pragma unroll
                for (int p = 0; p < 4; ++p) ins4u(m, o[p]);
            }
            if (l15 == 0) {
                const int row = m0 + set * 16 + quad * 4 + r;
#pragma unroll
                for (int p = 0; p < 4; ++p)
                    cand_i[((size_t)row * NCH + blockIdx.x) * 4 + p] = c0 + (int)(m[p] & 0x7FFu);
            }
        }
    }
}

// ---------- exact f32 re-rank of 368 candidates/row + weighted value gather (bf16 out) ----------
__global__ __launch_bounds__(256)
void rerank_gather(const int* __restrict__ cand_i, const float* __restrict__ cq,
                   const float* __restrict__ keysf, const float* __restrict__ qq,
                   const float* __restrict__ kk, const float* __restrict__ values,
                   ushort* __restrict__ wbf, float* __restrict__ conf_out) {
    __shared__ __align__(16) float qs[128];
    __shared__ float ed[NCAND];
    __shared__ int   ei[NCAND];
    __shared__ float w5[5];
    __shared__ int   s5[5];
    __shared__ float confs;
    const int row = blockIdx.x, tid = threadIdx.x;
    const int wv = tid >> 6, ln = tid & 63;
    if (tid < 128) qs[tid] = cq[(size_t)row * 128 + tid];
    for (int c = tid; c < NCAND; c += 256) ei[c] = cand_i[(size_t)row * NCAND + c];
    __syncthreads();
    const float2 q2 = *(const float2*)&qs[ln * 2];
    const float qqr = qq[row];
    for (int c = wv; c < NCAND; c += 4) {
        const int idx = ei[c];
        const int idc = idx < NKEYS ? idx : NKEYS - 1;     // padded cands: kk=BIGF kills them
        const float2 k2 = *(const float2*)&keysf[(size_t)idc * 128 + ln * 2];
        float dot = q2.x * k2.x + q2.y * k2.y;
#pragma unroll
        for (int off = 32; off > 0; off >>= 1) dot += __shfl_down(dot, off, 64);
        if (ln == 0) ed[c] = qqr + kk[idx] - 2.0f * dot;
    }
    __syncthreads();
    if (wv == 0) {
        float bd[5]; int bi[5];
#pragma unroll
        for (int p = 0; p < 5; ++p) { bd[p] = BIGF; bi[p] = 0; }
        for (int c = ln; c < NCAND; c += 64) ins5(bd, bi, ed[c], ei[c]);
#pragma unroll
        for (int m = 1; m <= 32; m <<= 1) {
            float od[5]; int oi[5];
#pragma unroll
            for (int p = 0; p < 5; ++p) {
                od[p] = __shfl_xor(bd[p], m, 64);
                oi[p] = __shfl_xor(bi[p], m, 64);
            }
#pragma unroll
            for (int p = 0; p < 5; ++p) ins5(bd, bi, od[p], oi[p]);
        }
        if (ln == 0) {
            float ww[5]; float s = 0.f;
#pragma unroll
            for (int p = 0; p < 5; ++p) { ww[p] = 1.0f / (bd[p] + EPS_F); s += ww[p]; }
#pragma unroll
            for (int p = 0; p < 5; ++p) { w5[p] = ww[p] / s; s5[p] = bi[p]; }
            confs = 1.0f / (bd[0] + EPS_F);
        }
    }
    __syncthreads();
    if (tid < 128) {
        float acc = 0.f;
#pragma unroll
        for (int p = 0; p < 5; ++p) acc += w5[p] * values[(size_t)s5[p] * 128 + tid];
        __hip_bfloat16 h = __float2bfloat16(acc);
        wbf[(size_t)row * 128 + tid] = *(ushort*)&h;
    }
    if (tid == 0) conf_out[row] = confs;
}

// ---------- bf16-MFMA GEMM for decompress MLP: C = act(A@W + b) ----------
// grid (N/64, M/128), block 256 = 4 waves x 32 rows. W panels (fragment-major image)
// double-buffered via global_load_lds; A-frags direct bf16x8 global loads.
template <int RELU, int OUTF32>
__global__ __launch_bounds__(256)
void bgemm_bias(const ushort* __restrict__ Abf, const uint4* __restrict__ Wimg,
                const float* __restrict__ bias, void* __restrict__ Cout,
                int M, int N, int K) {
    __shared__ uint4 pan[2][512];   // 2 x 8 KB weight panels
    const int tid = threadIdx.x;
    const int wv = tid >> 6, ln = tid & 63;
    const int quad = ln >> 4, l15 = ln & 15;
    const int n0 = blockIdx.x * 64;
    const int m0 = blockIdx.y * 128 + wv * 32;
    const int ctile = blockIdx.x, npan = K >> 6;
    f32x4 acc[2][4];
#pragma unroll
    for (int s = 0; s < 2; ++s)
#pragma unroll
        for (int c = 0; c < 4; ++c) acc[s][c] = (f32x4){0.f, 0.f, 0.f, 0.f};

#pragma unroll
    for (int it = 0; it < 2; ++it)
        gl_lds16(&Wimg[(size_t)ctile * npan * 512 + it * 256 + wv * 64 + ln],
                 &pan[0][it * 256 + wv * 64]);
    __syncthreads();

    for (int p = 0; p < npan; ++p) {
        const int b = p & 1;
        if (p + 1 < npan) {
#pragma unroll
            for (int it = 0; it < 2; ++it)
                gl_lds16(&Wimg[((size_t)ctile * npan + p + 1) * 512 + it * 256 + wv * 64 + ln],
                         &pan[b ^ 1][it * 256 + wv * 64]);
        }
        const ushort* arow = Abf + (size_t)(m0 + l15) * K + p * 64 + quad * 8;
        bf16x8 afA[2], afB[2];
#pragma unroll
        for (int s = 0; s < 2; ++s) {
            afA[s] = *(const bf16x8*)(arow + s * 32);
            afB[s] = *(const bf16x8*)(arow + (size_t)16 * K + s * 32);
        }
#pragma unroll
        for (int ct = 0; ct < 4; ++ct)
#pragma unroll
            for (int s = 0; s < 2; ++s) {
                bf16x8 bfr = *(const bf16x8*)&pan[b][((ct * 2 + s) * 4 + quad) * 16 + l15];
                acc[0][ct] = __builtin_amdgcn_mfma_f32_16x16x32_bf16(afA[s], bfr, acc[0][ct], 0, 0, 0);
                acc[1][ct] = __builtin_amdgcn_mfma_f32_16x16x32_bf16(afB[s], bfr, acc[1][ct], 0, 0, 0);
            }
        __syncthreads();
    }

#pragma unroll
    for (int ct = 0; ct < 4; ++ct) {
        const int col = n0 + ct * 16 + l15;
        const float bv = bias[col];
#pragma unroll
        for (int set = 0; set < 2; ++set)
#pragma unroll
            for (int r = 0; r < 4; ++r) {
                float v = acc[set][ct][r] + bv;
                if (RELU) v = fmaxf(v, 0.f);
                const int row = m0 + set * 16 + quad * 4 + r;
                if (OUTF32) {
                    ((float*)Cout)[(size_t)row * N + col] = v;
                } else {
                    __hip_bfloat16 h = __float2bfloat16(v);
                    ((ushort*)Cout)[(size_t)row * N + col] = *(ushort*)&h;
                }
            }
    }
}

extern "C" void kernel_launch(void* const* d_in, const int* in_sizes, int n_in,
                              void* d_out, int out_size, void* d_ws, size_t ws_size,
                              hipStream_t stream) {
    const float* query  = (const float*)d_in[0];
    const float* W1     = (const float*)d_in[1];
    const float* b1     = (const float*)d_in[2];
    const float* W2     = (const float*)d_in[3];
    const float* b2     = (const float*)d_in[4];
    const float* W3     = (const float*)d_in[5];
    const float* b3     = (const float*)d_in[6];
    const float* keys   = (const float*)d_in[7];
    const float* values = (const float*)d_in[8];
    const float* D1w    = (const float*)d_in[9];
    const float* D1b    = (const float*)d_in[10];
    const float* D2w    = (const float*)d_in[11];
    const float* D2b    = (const float*)d_in[12];
    const float* D3w    = (const float*)d_in[13];
    const float* D3b    = (const float*)d_in[14];
    float* out = (float*)d_out;

    // workspace layout (f32 words), ~37 MB total
    float*  ws    = (float*)d_ws;
    float*  kk    = ws;                        // 100096
    float*  khalf = ws + 100096;               // 100096
    float*  qq    = ws + 200192;               // 1024
    float*  cq    = ws + 201216;               // 131072
    ushort* qbf   = (ushort*)(ws + 332288);    // 131072 ushort
    float*  h1    = ws + 397824;               // 524288
    float*  h2    = ws + 922112;               // 262144
    float*  part  = ws + 1184256;              // 2097152 (8 MB split-K partials; overlaid below)
    uint4*  img   = (uint4*)(ws + 3281408);    // 6406144 words bf16 key image
    // overlays inside part (all first written after the compress MLP finishes):
    int*    cand  = (int*)part;                           // 1024*368 = 376832 w
    ushort* wbf   = (ushort*)(part + 376832);             // 65536 w
    ushort* h3bf  = (ushort*)(part + 442368);             // 131072 w
    ushort* h4bf  = (ushort*)(part + 573440);             // 262144 w
    uint4*  Wimg1 = (uint4*)(part + 835584);              // 16384 w
    uint4*  Wimg2 = (uint4*)(part + 851968);              // 65536 w
    uint4*  Wimg3 = (uint4*)(part + 917504);              // 262144 w
    float*  conf  = out + 1024 * 1024;

    cvt_keys<<<NTILE, 256, 0, stream>>>(keys, img, kk, khalf);
    // compress MLP (f32, split-K — selection-exactness requires f32 here)
    sgemm_part<<<dim3(8, 16, 4), 256, 0, stream>>>(query, W1, part, 1024, 512, 1024, 256);
    reduce_bias<1><<<512, 256, 0, stream>>>(part, b1, h1, 1024 * 512, 512, 4);
    sgemm_part<<<dim3(4, 16, 8), 256, 0, stream>>>(h1, W2, part, 1024, 256, 512, 64);
    reduce_bias<1><<<256, 256, 0, stream>>>(part, b2, h2, 1024 * 256, 256, 8);
    sgemm_part<<<dim3(2, 16, 8), 256, 0, stream>>>(h2, W3, part, 1024, 128, 256, 32);
    reduce_bias<0><<<128, 256, 0, stream>>>(part, b3, cq, 1024 * 128, 128, 8);
    // decompress weight images (after last read of split-K partials)
    cvt_wT<<<dim3(4, 2),  256, 0, stream>>>(D1w, Wimg1, 128, 256);
    cvt_wT<<<dim3(8, 4),  256, 0, stream>>>(D2w, Wimg2, 256, 512);
    cvt_wT<<<dim3(16, 8), 256, 0, stream>>>(D3w, Wimg3, 512, 1024);
    rowsq128<<<256, 256, 0, stream>>>(cq, qq, BQ);
    cvt_bf16_rne<<<128, 256, 0, stream>>>(cq, qbf, BQ * 128);
    // retrieval
    screen_topk<<<dim3(NCH, BQ / 128), 256, 0, stream>>>(qbf, img, khalf, cand);
    rerank_gather<<<BQ, 256, 0, stream>>>(cand, cq, keys, qq, kk, values, wbf, conf);
    // decompress MLP (bf16 MFMA)
    bgemm_bias<1, 0><<<dim3(4, 8),  256, 0, stream>>>(wbf,  Wimg1, D1b, h3bf, 1024, 256,  128);
    bgemm_bias<1, 0><<<dim3(8, 8),  256, 0, stream>>>(h3bf, Wimg2, D2b, h4bf, 1024, 512,  256);
    bgemm_bias<0, 1><<<dim3(16, 8), 256, 0, stream>>>(h4bf, Wimg3, D3b, out,  1024, 1024, 512);

    (void)in_sizes; (void)n_in; (void)out_size; (void)ws_size;
}

// Round 5
// 301.682 us; speedup vs baseline: 4.2173x; 1.1575x over previous
//
#include <hip/hip_runtime.h>
#include <hip/hip_bf16.h>

#define NKEYS  100000
#define NCH    92
#define CHK    1088            // 17 tiles of 64 keys
#define TPC    17              // tiles per chunk
#define KPAD   (NCH * CHK)     // 100096
#define NTILE  (KPAD / 64)     // 1564
#define BQ     1024
#define EPS_F  1e-6f
#define NCAND  (NCH * 4)       // 368 candidates per row
#define BIGF   1e30f

typedef __attribute__((ext_vector_type(8))) short bf16x8;
typedef __attribute__((ext_vector_type(4))) float f32x4;

__device__ __forceinline__ void gl_lds16(const uint4* g, uint4* l) {
    __builtin_amdgcn_global_load_lds((const __attribute__((address_space(1))) void*)g,
                                     (__attribute__((address_space(3))) void*)l, 16, 0, 0);
}
__device__ __forceinline__ unsigned umn(unsigned a, unsigned b) { return a < b ? a : b; }
__device__ __forceinline__ unsigned umx(unsigned a, unsigned b) { return a > b ? a : b; }

// branchless insert into ascending sorted top-3 of packed uints (5 min/max)
__device__ __forceinline__ void ins3u(unsigned (&m)[3], unsigned u) {
    unsigned v1 = umn(m[2], u);
    m[2] = umx(m[1], v1);
    unsigned v2 = umn(m[1], v1);
    m[1] = umx(m[0], v2);
    m[0] = umn(m[0], v2);
}
// branchless insert into ascending sorted top-4 (7 min/max)
__device__ __forceinline__ void ins4u(unsigned (&m)[4], unsigned u) {
    unsigned v1 = umn(m[3], u);
    m[3] = umx(m[2], v1);
    unsigned v2 = umn(m[2], v1);
    m[2] = umx(m[1], v2);
    unsigned v3 = umn(m[1], v2);
    m[1] = umx(m[0], v3);
    m[0] = umn(m[0], v3);
}

// f32 (dist,idx) sorted top-5 insert (rerank only — off the hot path)
__device__ __forceinline__ void ins5(float (&d)[5], int (&ix)[5], float nd, int ni) {
    if (nd < d[4]) {
        d[4] = nd; ix[4] = ni;
#pragma unroll
        for (int p = 4; p > 0; --p) {
            if (d[p] < d[p - 1]) {
                float td = d[p]; d[p] = d[p - 1]; d[p - 1] = td;
                int   ti = ix[p]; ix[p] = ix[p - 1]; ix[p - 1] = ti;
            }
        }
    }
}

// ---------- one-time key preprocessing: fragment-major bf16 image + kk + (-kk/2) ----------
__global__ __launch_bounds__(256)
void cvt_keys(const float* __restrict__ keys, uint4* __restrict__ img,
              float* __restrict__ kk, float* __restrict__ khalf) {
    const int tid = threadIdx.x;
    const int r = tid >> 2, s = tid & 3;
    const int tile = blockIdx.x;
    const int n = tile * 64 + r;
    const int ct = r >> 4, l15 = r & 15;
    const bool live = (n < NKEYS);
    const float* kp = keys + (size_t)n * 128 + s * 32;
    float ss = 0.f;
    uint4 out[4];
#pragma unroll
    for (int q = 0; q < 4; ++q) {
        float4 a = make_float4(0.f, 0.f, 0.f, 0.f), b = a;
        if (live) { a = *(const float4*)(kp + q * 8); b = *(const float4*)(kp + q * 8 + 4); }
        ss += a.x * a.x + a.y * a.y + a.z * a.z + a.w * a.w
            + b.x * b.x + b.y * b.y + b.z * b.z + b.w * b.w;
        float v[8] = {a.x, a.y, a.z, a.w, b.x, b.y, b.z, b.w};
        ushort h[8];
#pragma unroll
        for (int j = 0; j < 8; ++j) {
            __hip_bfloat16 t = __float2bfloat16(v[j]);
            h[j] = *(ushort*)&t;
        }
        out[q] = make_uint4((uint)h[0] | ((uint)h[1] << 16), (uint)h[2] | ((uint)h[3] << 16),
                            (uint)h[4] | ((uint)h[5] << 16), (uint)h[6] | ((uint)h[7] << 16));
    }
    ss += __shfl_xor(ss, 1, 64);
    ss += __shfl_xor(ss, 2, 64);
    if (s == 0) {
        kk[n]    = live ? ss : BIGF;
        khalf[n] = live ? -0.5f * ss : -BIGF;
    }
#pragma unroll
    for (int q = 0; q < 4; ++q)
        img[(size_t)tile * 1024 + ((ct * 4 + s) * 4 + q) * 16 + l15] = out[q];
}

// ---------- split-K f32 GEMM + reduce (compress MLP must stay f32-exact) ----------
__global__ __launch_bounds__(256)
void sgemm_part(const float* __restrict__ A, const float* __restrict__ W,
                float* __restrict__ P, int M, int N, int K, int kslice) {
    __shared__ float As[16][68];
    __shared__ float Bs[16][64];
    const int tid = threadIdx.x;
    const int tx = tid & 15, ty = tid >> 4;
    const int m0 = blockIdx.y * 64, n0 = blockIdx.x * 64;
    const int kb = blockIdx.z * kslice, ke = kb + kslice;
    float acc[4][4] = {};
    for (int k0 = kb; k0 < ke; k0 += 16) {
        {
            int m = tid >> 2, k4 = (tid & 3) * 4;
            float4 a = *(const float4*)&A[(size_t)(m0 + m) * K + k0 + k4];
            As[k4 + 0][m] = a.x; As[k4 + 1][m] = a.y;
            As[k4 + 2][m] = a.z; As[k4 + 3][m] = a.w;
        }
        {
            int k = tid >> 4, n4 = (tid & 15) * 4;
            *(float4*)&Bs[k][n4] = *(const float4*)&W[(size_t)(k0 + k) * N + n0 + n4];
        }
        __syncthreads();
#pragma unroll
        for (int kkk = 0; kkk < 16; ++kkk) {
            float4 a4 = *(const float4*)&As[kkk][ty * 4];
            float4 b4 = *(const float4*)&Bs[kkk][tx * 4];
            float av[4] = {a4.x, a4.y, a4.z, a4.w};
            float bv[4] = {b4.x, b4.y, b4.z, b4.w};
#pragma unroll
            for (int i = 0; i < 4; ++i)
#pragma unroll
                for (int j = 0; j < 4; ++j)
                    acc[i][j] = fmaf(av[i], bv[j], acc[i][j]);
        }
        __syncthreads();
    }
    P += (size_t)blockIdx.z * M * N;
#pragma unroll
    for (int i = 0; i < 4; ++i)
        *(float4*)&P[(size_t)(m0 + ty * 4 + i) * N + n0 + tx * 4] =
            make_float4(acc[i][0], acc[i][1], acc[i][2], acc[i][3]);
}

template <int RELU>
__global__ __launch_bounds__(256)
void reduce_bias(const float* __restrict__ P, const float* __restrict__ bias,
                 float* __restrict__ C, int MN, int N, int nP) {
    int i4 = (blockIdx.x * 256 + threadIdx.x) * 4;
    if (i4 >= MN) return;
    float4 s = *(const float4*)&P[i4];
    for (int p = 1; p < nP; ++p) {
        float4 v = *(const float4*)&P[(size_t)p * MN + i4];
        s.x += v.x; s.y += v.y; s.z += v.z; s.w += v.w;
    }
    float4 b = *(const float4*)&bias[i4 % N];
    s.x += b.x; s.y += b.y; s.z += b.z; s.w += b.w;
    if (RELU) {
        s.x = fmaxf(s.x, 0.f); s.y = fmaxf(s.y, 0.f);
        s.z = fmaxf(s.z, 0.f); s.w = fmaxf(s.w, 0.f);
    }
    *(float4*)&C[i4] = s;
}

__global__ __launch_bounds__(256)
void rowsq128(const float* __restrict__ X, float* __restrict__ out, int nrows) {
    int lane = threadIdx.x & 63;
    int row  = blockIdx.x * 4 + (threadIdx.x >> 6);
    if (row >= nrows) return;
    const float* x = X + (size_t)row * 128;
    float a = x[lane], b = x[lane + 64];
    float v = a * a + b * b;
#pragma unroll
    for (int off = 32; off > 0; off >>= 1) v += __shfl_down(v, off, 64);
    if (lane == 0) out[row] = v;
}

__global__ __launch_bounds__(256)
void cvt_bf16_rne(const float* __restrict__ in, ushort* __restrict__ out, int n) {
    int i = (blockIdx.x * 256 + threadIdx.x) * 4;
    if (i >= n) return;
    float4 v = *(const float4*)&in[i];
    __hip_bfloat16 h0 = __float2bfloat16(v.x), h1 = __float2bfloat16(v.y);
    __hip_bfloat16 h2 = __float2bfloat16(v.z), h3 = __float2bfloat16(v.w);
    ushort4 o;
    o.x = *(ushort*)&h0; o.y = *(ushort*)&h1; o.z = *(ushort*)&h2; o.w = *(ushort*)&h3;
    *(ushort4*)&out[i] = o;
}

// ---------- weight -> fragment-major bf16 image (for decompress MFMA GEMMs) ----------
__global__ __launch_bounds__(256)
void cvt_wT(const float* __restrict__ W, uint4* __restrict__ Wimg, int K, int N) {
    const int ctile = blockIdx.x, p = blockIdx.y;
    const int npan = K >> 6;
#pragma unroll
    for (int it = 0; it < 2; ++it) {
        int c = it * 256 + threadIdx.x;
        int l15 = c & 15, quad = (c >> 4) & 3, s = (c >> 6) & 1, ct = c >> 7;
        int n = ctile * 64 + ct * 16 + l15;
        int k = p * 64 + s * 32 + quad * 8;
        ushort h[8];
#pragma unroll
        for (int j = 0; j < 8; ++j) {
            __hip_bfloat16 t = __float2bfloat16(W[(size_t)(k + j) * N + n]);
            h[j] = *(ushort*)&t;
        }
        Wimg[((size_t)ctile * npan + p) * 512 + c] =
            make_uint4((uint)h[0] | ((uint)h[1] << 16), (uint)h[2] | ((uint)h[3] << 16),
                       (uint)h[4] | ((uint)h[5] << 16), (uint)h[6] | ((uint)h[7] << 16));
    }
}

// ---------- bf16-MFMA screening with packed-uint branchless top-3 scan ----------
__global__ __launch_bounds__(256, 3)
void screen_topk(const ushort* __restrict__ qbf, const uint4* __restrict__ img,
                 const float* __restrict__ khalf, int* __restrict__ cand_i) {
    __shared__ uint4 buf[2][1024];   // 2 x 16 KB key tiles
    __shared__ float kls[CHK];       // -kk/2 for chunk
    const int tid = threadIdx.x;
    const int wv = tid >> 6, ln = tid & 63;
    const int quad = ln >> 4, l15 = ln & 15;
    const int m0 = blockIdx.y * 128 + wv * 32;
    const int c0 = blockIdx.x * CHK;
    const int t0 = blockIdx.x * TPC;

    bf16x8 afA[4], afB[4];
    {
        const ushort* qa = qbf + (size_t)(m0 + l15) * 128 + quad * 8;
#pragma unroll
        for (int s = 0; s < 4; ++s) {
            afA[s] = *(const bf16x8*)(qa + 32 * s);
            afB[s] = *(const bf16x8*)(qa + 16 * 128 + 32 * s);
        }
    }
    for (int i = tid; i < CHK; i += 256) kls[i] = khalf[c0 + i];

    unsigned mA[4][3], mB[4][3];
#pragma unroll
    for (int r = 0; r < 4; ++r)
#pragma unroll
        for (int p = 0; p < 3; ++p) { mA[r][p] = 0xFFFFFFFFu; mB[r][p] = 0xFFFFFFFFu; }

#pragma unroll
    for (int it = 0; it < 4; ++it)
        gl_lds16(&img[(size_t)t0 * 1024 + it * 256 + wv * 64 + ln], &buf[0][it * 256 + wv * 64]);
    __syncthreads();

    for (int t = 0; t < TPC; ++t) {
        const int b = t & 1;
        if (t + 1 < TPC) {
#pragma unroll
            for (int it = 0; it < 4; ++it)
                gl_lds16(&img[(size_t)(t0 + t + 1) * 1024 + it * 256 + wv * 64 + ln],
                         &buf[b ^ 1][it * 256 + wv * 64]);
        }
#pragma unroll
        for (int ct = 0; ct < 4; ++ct) {
            const int nl = t * 64 + ct * 16 + l15;
            const float kh = kls[nl];
            f32x4 a0 = {kh, kh, kh, kh}, a1 = {kh, kh, kh, kh};
#pragma unroll
            for (int s = 0; s < 4; ++s) {
                bf16x8 bfr = *(const bf16x8*)&buf[b][(ct * 4 + s) * 64 + ln];
                a0 = __builtin_amdgcn_mfma_f32_16x16x32_bf16(afA[s], bfr, a0, 0, 0, 0);
                a1 = __builtin_amdgcn_mfma_f32_16x16x32_bf16(afB[s], bfr, a1, 0, 0, 0);
            }
#pragma unroll
            for (int r = 0; r < 4; ++r) {
                ins3u(mA[r], (__float_as_uint(a0[r]) & 0xFFFFF800u) | (unsigned)nl);
                ins3u(mB[r], (__float_as_uint(a1[r]) & 0xFFFFF800u) | (unsigned)nl);
            }
        }
        __syncthreads();
    }

#pragma unroll
    for (int set = 0; set < 2; ++set) {
#pragma unroll
        for (int r = 0; r < 4; ++r) {
            unsigned m[4];
#pragma unroll
            for (int p = 0; p < 3; ++p) m[p] = set ? mB[r][p] : mA[r][p];
            m[3] = 0xFFFFFFFFu;
#pragma unroll
            for (int st = 1; st <= 8; st <<= 1) {
                unsigned o[4];
#pragma unroll
                for (int p = 0; p < 4; ++p) o[p] = (unsigned)__shfl_xor((int)m[p], st, 64);
#pragma unroll
                for (int p = 0; p < 4; ++p) ins4u(m, o[p]);
            }
            if (l15 == 0) {
                const int row = m0 + set * 16 + quad * 4 + r;
#pragma unroll
                for (int p = 0; p < 4; ++p)
                    cand_i[((size_t)row * NCH + blockIdx.x) * 4 + p] = c0 + (int)(m[p] & 0x7FFu);
            }
        }
    }
}

// ---------- exact f32 re-rank: quad-per-candidate, 512 threads/block ----------
// One block per query row. Each 16-lane quad owns one candidate per iteration:
// lane l15 reads dims l15*8..+7 (512B coalesced per quad), 4-step xor-reduce.
// 32 quads/block -> 12 iterations; 8 waves/block -> full CU occupancy, 32+
// loads in flight. Replaces the latency-bound wave-per-candidate version
// (92 serial iters, 6-step reduce, 42% occupancy, VALUBusy 17%).
__global__ __launch_bounds__(512)
void rerank_gather(const int* __restrict__ cand_i, const float* __restrict__ cq,
                   const float* __restrict__ keysf, const float* __restrict__ qq,
                   const float* __restrict__ kk, const float* __restrict__ values,
                   ushort* __restrict__ wbf, float* __restrict__ conf_out) {
    __shared__ __align__(16) float qs[128];
    __shared__ float ed[NCAND];
    __shared__ int   ei[NCAND];
    __shared__ float w5[5];
    __shared__ int   s5[5];
    __shared__ float confs;
    const int row = blockIdx.x, tid = threadIdx.x;
    const int ln = tid & 63;
    const int qd = tid >> 4;        // global quad id 0..31
    const int l15 = tid & 15;
    if (tid < 128) qs[tid] = cq[(size_t)row * 128 + tid];
    for (int c = tid; c < NCAND; c += 512) ei[c] = cand_i[(size_t)row * NCAND + c];
    __syncthreads();
    const float4 qa = *(const float4*)&qs[l15 * 8];
    const float4 qb = *(const float4*)&qs[l15 * 8 + 4];
    const float qqr = qq[row];
#pragma unroll 3
    for (int it = 0; it < (NCAND + 31) / 32; ++it) {
        const int c = qd + it * 32;
        if (c < NCAND) {
            const int idx = ei[c];
            const float* kp = &keysf[(size_t)idx * 128 + l15 * 8];
            const float4 ka = *(const float4*)kp;
            const float4 kb = *(const float4*)(kp + 4);
            float dot = qa.x * ka.x + qa.y * ka.y + qa.z * ka.z + qa.w * ka.w
                      + qb.x * kb.x + qb.y * kb.y + qb.z * kb.z + qb.w * kb.w;
            dot += __shfl_xor(dot, 1, 64);
            dot += __shfl_xor(dot, 2, 64);
            dot += __shfl_xor(dot, 4, 64);
            dot += __shfl_xor(dot, 8, 64);
            if (l15 == 0) ed[c] = qqr + kk[idx] - 2.0f * dot;
        }
    }
    __syncthreads();
    if (tid < 64) {   // wave 0: final exact top-5 over 368 candidates
        float bd[5]; int bi[5];
#pragma unroll
        for (int p = 0; p < 5; ++p) { bd[p] = BIGF; bi[p] = 0; }
        for (int c = ln; c < NCAND; c += 64) ins5(bd, bi, ed[c], ei[c]);
#pragma unroll
        for (int m = 1; m <= 32; m <<= 1) {
            float od[5]; int oi[5];
#pragma unroll
            for (int p = 0; p < 5; ++p) {
                od[p] = __shfl_xor(bd[p], m, 64);
                oi[p] = __shfl_xor(bi[p], m, 64);
            }
#pragma unroll
            for (int p = 0; p < 5; ++p) ins5(bd, bi, od[p], oi[p]);
        }
        if (ln == 0) {
            float ww[5]; float s = 0.f;
#pragma unroll
            for (int p = 0; p < 5; ++p) { ww[p] = 1.0f / (bd[p] + EPS_F); s += ww[p]; }
#pragma unroll
            for (int p = 0; p < 5; ++p) { w5[p] = ww[p] / s; s5[p] = bi[p]; }
            confs = 1.0f / (bd[0] + EPS_F);
        }
    }
    __syncthreads();
    if (tid < 128) {
        float acc = 0.f;
#pragma unroll
        for (int p = 0; p < 5; ++p) acc += w5[p] * values[(size_t)s5[p] * 128 + tid];
        __hip_bfloat16 h = __float2bfloat16(acc);
        wbf[(size_t)row * 128 + tid] = *(ushort*)&h;
    }
    if (tid == 0) conf_out[row] = confs;
}

// ---------- bf16-MFMA GEMM for decompress MLP: C = act(A@W + b) ----------
template <int RELU, int OUTF32>
__global__ __launch_bounds__(256)
void bgemm_bias(const ushort* __restrict__ Abf, const uint4* __restrict__ Wimg,
                const float* __restrict__ bias, void* __restrict__ Cout,
                int M, int N, int K) {
    __shared__ uint4 pan[2][512];   // 2 x 8 KB weight panels
    const int tid = threadIdx.x;
    const int wv = tid >> 6, ln = tid & 63;
    const int quad = ln >> 4, l15 = ln & 15;
    const int n0 = blockIdx.x * 64;
    const int m0 = blockIdx.y * 128 + wv * 32;
    const int ctile = blockIdx.x, npan = K >> 6;
    f32x4 acc[2][4];
#pragma unroll
    for (int s = 0; s < 2; ++s)
#pragma unroll
        for (int c = 0; c < 4; ++c) acc[s][c] = (f32x4){0.f, 0.f, 0.f, 0.f};

#pragma unroll
    for (int it = 0; it < 2; ++it)
        gl_lds16(&Wimg[(size_t)ctile * npan * 512 + it * 256 + wv * 64 + ln],
                 &pan[0][it * 256 + wv * 64]);
    __syncthreads();

    for (int p = 0; p < npan; ++p) {
        const int b = p & 1;
        if (p + 1 < npan) {
#pragma unroll
            for (int it = 0; it < 2; ++it)
                gl_lds16(&Wimg[((size_t)ctile * npan + p + 1) * 512 + it * 256 + wv * 64 + ln],
                         &pan[b ^ 1][it * 256 + wv * 64]);
        }
        const ushort* arow = Abf + (size_t)(m0 + l15) * K + p * 64 + quad * 8;
        bf16x8 afA[2], afB[2];
#pragma unroll
        for (int s = 0; s < 2; ++s) {
            afA[s] = *(const bf16x8*)(arow + s * 32);
            afB[s] = *(const bf16x8*)(arow + (size_t)16 * K + s * 32);
        }
#pragma unroll
        for (int ct = 0; ct < 4; ++ct)
#pragma unroll
            for (int s = 0; s < 2; ++s) {
                bf16x8 bfr = *(const bf16x8*)&pan[b][((ct * 2 + s) * 4 + quad) * 16 + l15];
                acc[0][ct] = __builtin_amdgcn_mfma_f32_16x16x32_bf16(afA[s], bfr, acc[0][ct], 0, 0, 0);
                acc[1][ct] = __builtin_amdgcn_mfma_f32_16x16x32_bf16(afB[s], bfr, acc[1][ct], 0, 0, 0);
            }
        __syncthreads();
    }

#pragma unroll
    for (int ct = 0; ct < 4; ++ct) {
        const int col = n0 + ct * 16 + l15;
        const float bv = bias[col];
#pragma unroll
        for (int set = 0; set < 2; ++set)
#pragma unroll
            for (int r = 0; r < 4; ++r) {
                float v = acc[set][ct][r] + bv;
                if (RELU) v = fmaxf(v, 0.f);
                const int row = m0 + set * 16 + quad * 4 + r;
                if (OUTF32) {
                    ((float*)Cout)[(size_t)row * N + col] = v;
                } else {
                    __hip_bfloat16 h = __float2bfloat16(v);
                    ((ushort*)Cout)[(size_t)row * N + col] = *(ushort*)&h;
                }
            }
    }
}

extern "C" void kernel_launch(void* const* d_in, const int* in_sizes, int n_in,
                              void* d_out, int out_size, void* d_ws, size_t ws_size,
                              hipStream_t stream) {
    const float* query  = (const float*)d_in[0];
    const float* W1     = (const float*)d_in[1];
    const float* b1     = (const float*)d_in[2];
    const float* W2     = (const float*)d_in[3];
    const float* b2     = (const float*)d_in[4];
    const float* W3     = (const float*)d_in[5];
    const float* b3     = (const float*)d_in[6];
    const float* keys   = (const float*)d_in[7];
    const float* values = (const float*)d_in[8];
    const float* D1w    = (const float*)d_in[9];
    const float* D1b    = (const float*)d_in[10];
    const float* D2w    = (const float*)d_in[11];
    const float* D2b    = (const float*)d_in[12];
    const float* D3w    = (const float*)d_in[13];
    const float* D3b    = (const float*)d_in[14];
    float* out = (float*)d_out;

    // workspace layout (f32 words), ~37 MB total
    float*  ws    = (float*)d_ws;
    float*  kk    = ws;                        // 100096
    float*  khalf = ws + 100096;               // 100096
    float*  qq    = ws + 200192;               // 1024
    float*  cq    = ws + 201216;               // 131072
    ushort* qbf   = (ushort*)(ws + 332288);    // 131072 ushort
    float*  h1    = ws + 397824;               // 524288
    float*  h2    = ws + 922112;               // 262144
    float*  part  = ws + 1184256;              // 2097152 (8 MB split-K partials; overlaid below)
    uint4*  img   = (uint4*)(ws + 3281408);    // 6406144 words bf16 key image
    // overlays inside part (all first written after the compress MLP finishes):
    int*    cand  = (int*)part;                           // 1024*368 = 376832 w
    ushort* wbf   = (ushort*)(part + 376832);             // 65536 w
    ushort* h3bf  = (ushort*)(part + 442368);             // 131072 w
    ushort* h4bf  = (ushort*)(part + 573440);             // 262144 w
    uint4*  Wimg1 = (uint4*)(part + 835584);              // 16384 w
    uint4*  Wimg2 = (uint4*)(part + 851968);              // 65536 w
    uint4*  Wimg3 = (uint4*)(part + 917504);              // 262144 w
    float*  conf  = out + 1024 * 1024;

    cvt_keys<<<NTILE, 256, 0, stream>>>(keys, img, kk, khalf);
    // compress MLP (f32, split-K — selection-exactness requires f32 here)
    sgemm_part<<<dim3(8, 16, 4), 256, 0, stream>>>(query, W1, part, 1024, 512, 1024, 256);
    reduce_bias<1><<<512, 256, 0, stream>>>(part, b1, h1, 1024 * 512, 512, 4);
    sgemm_part<<<dim3(4, 16, 8), 256, 0, stream>>>(h1, W2, part, 1024, 256, 512, 64);
    reduce_bias<1><<<256, 256, 0, stream>>>(part, b2, h2, 1024 * 256, 256, 8);
    sgemm_part<<<dim3(2, 16, 8), 256, 0, stream>>>(h2, W3, part, 1024, 128, 256, 32);
    reduce_bias<0><<<128, 256, 0, stream>>>(part, b3, cq, 1024 * 128, 128, 8);
    // decompress weight images (after last read of split-K partials)
    cvt_wT<<<dim3(4, 2),  256, 0, stream>>>(D1w, Wimg1, 128, 256);
    cvt_wT<<<dim3(8, 4),  256, 0, stream>>>(D2w, Wimg2, 256, 512);
    cvt_wT<<<dim3(16, 8), 256, 0, stream>>>(D3w, Wimg3, 512, 1024);
    rowsq128<<<256, 256, 0, stream>>>(cq, qq, BQ);
    cvt_bf16_rne<<<128, 256, 0, stream>>>(cq, qbf, BQ * 128);
    // retrieval
    screen_topk<<<dim3(NCH, BQ / 128), 256, 0, stream>>>(qbf, img, khalf, cand);
    rerank_gather<<<BQ, 512, 0, stream>>>(cand, cq, keys, qq, kk, values, wbf, conf);
    // decompress MLP (bf16 MFMA)
    bgemm_bias<1, 0><<<dim3(4, 8),  256, 0, stream>>>(wbf,  Wimg1, D1b, h3bf, 1024, 256,  128);
    bgemm_bias<1, 0><<<dim3(8, 8),  256, 0, stream>>>(h3bf, Wimg2, D2b, h4bf, 1024, 512,  256);
    bgemm_bias<0, 1><<<dim3(16, 8), 256, 0, stream>>>(h4bf, Wimg3, D3b, out,  1024, 1024, 512);

    (void)in_sizes; (void)n_in; (void)out_size; (void)ws_size;
}